// Round 1
// baseline (885.649 us; speedup 1.0000x reference)
//
#include <hip/hip_runtime.h>
#include <math.h>

#define NH 8
#define BITS_ 5
#define NB 40      // NH*BITS
#define TS 64
#define MAUG 27
#define CIN 64
#define HH 56
#define WW 56
#define NN 32
#define OCH 256
#define DK 576     // CIN*3*3
#define DPM 603    // DK + MAUG
#define HW (HH*WW)

// ---------------- Kernel A: hash the 256 kernel vectors (1 block) ----------------
__global__ void kA(const float* __restrict__ kern, const float* __restrict__ a,
                   float* __restrict__ aT, float* __restrict__ tcw,
                   int* __restrict__ bucket_k, int* __restrict__ tallied)
{
    const int t = threadIdx.x;
    // transpose a: aT[d*NB + j] = a[j*DPM + d]
    for (int idx = t; idx < DPM * NB; idx += 256) {
        int d = idx / NB, j = idx - d * NB;
        aT[idx] = a[j * DPM + d];
    }
    // constant-0.5-plane per-tap terms: tcw[tap*NB + j] = 0.5*sum_{mc=0..2} a[j, DK + mc*9 + tap]
    for (int idx = t; idx < 9 * NB; idx += 256) {
        int tap = idx / NB, j = idx - tap * NB;
        tcw[idx] = 0.5f * (a[j * DPM + DK + tap] + a[j * DPM + DK + 9 + tap] +
                           a[j * DPM + DK + 18 + tap]);
    }
    // zero vote histogram
    for (int idx = t; idx < NH * TS; idx += 256) tallied[idx] = 0;

    // max kernel norm -> scale
    __shared__ float s_red[256];
    float sq = 0.f;
    for (int d = 0; d < DK; ++d) { float v = kern[t * DK + d]; sq += v * v; }
    s_red[t] = sq;
    __syncthreads();
    for (int s = 128; s > 0; s >>= 1) {
        if (t < s) s_red[t] = fmaxf(s_red[t], s_red[t + s]);
        __syncthreads();
    }
    const float scale = 0.83f / sqrtf(s_red[0]);

    // projections of P(scale*kv) onto the 40 hash rows
    float acc[NB];
    #pragma unroll
    for (int j = 0; j < NB; ++j) acc[j] = 0.f;
    float p = 0.f;
    for (int d = 0; d < DK; ++d) {
        float xv = scale * kern[t * DK + d];
        p += xv * xv;
        const float* wp = &aT[d * NB];
        #pragma unroll
        for (int j = 0; j < NB; ++j) acc[j] += xv * wp[j];
    }
    float pv = p;  // augmentation cols: p, p^2, p^4, ...
    for (int m = 0; m < MAUG; ++m) {
        const float* wp = &aT[(DK + m) * NB];
        #pragma unroll
        for (int j = 0; j < NB; ++j) acc[j] += pv * wp[j];
        pv = pv * pv;
    }
    #pragma unroll
    for (int h = 0; h < NH; ++h) {
        int b = 0;
        #pragma unroll
        for (int bb = 0; bb < BITS_; ++bb)
            if (acc[h * BITS_ + bb] > 0.f) b |= (1 << bb);
        bucket_k[h * OCH + t] = b & (TS - 1);
    }
}

// ---------------- Kernel B: vote conv + per-hash histogram ----------------
__global__ void __launch_bounds__(256) kB(const float* __restrict__ x,
        const float* __restrict__ aT, const float* __restrict__ tcw,
        int* __restrict__ tallied)
{
    const int lane = threadIdx.x;           // 0..63, pixel x, active < 56
    const int ty = threadIdx.y;             // 0..3
    const int y = blockIdx.x * 4 + ty;      // 0..55
    const int n = blockIdx.y;
    const int xx = lane;
    const bool act = (xx < WW);

    float acc[NB];
    #pragma unroll
    for (int j = 0; j < NB; ++j) acc[j] = 0.f;

    const float* xb = x + (size_t)n * CIN * HW;
    for (int c = 0; c < CIN; ++c) {
        const float* xc = xb + c * HW;
        float xv[9];
        #pragma unroll
        for (int ky = 0; ky < 3; ++ky) {
            int yy = y + ky - 1;
            bool vy = (yy >= 0) && (yy < HH);
            #pragma unroll
            for (int kx = 0; kx < 3; ++kx) {
                int x2 = xx + kx - 1;
                bool v = act && vy && (x2 >= 0) && (x2 < WW);
                xv[ky * 3 + kx] = v ? xc[yy * WW + x2] : 0.f;
            }
        }
        #pragma unroll
        for (int tap = 0; tap < 9; ++tap) {
            const float* wp = &aT[(c * 9 + tap) * NB];  // uniform -> scalar loads
            #pragma unroll
            for (int j = 0; j < NB; ++j) acc[j] += xv[tap] * wp[j];
        }
    }
    // constant-0.5 planes (zero-padded at borders -> per-tap validity)
    #pragma unroll
    for (int tap = 0; tap < 9; ++tap) {
        int ky = tap / 3, kx = tap - ky * 3;
        int yy = y + ky - 1, x2 = xx + kx - 1;
        if (act && yy >= 0 && yy < HH && x2 >= 0 && x2 < WW) {
            const float* wp = &tcw[tap * NB];
            #pragma unroll
            for (int j = 0; j < NB; ++j) acc[j] += wp[j];
        }
    }

    __shared__ int hist[NH * TS];
    const int t = ty * 64 + lane;
    for (int i = t; i < NH * TS; i += 256) hist[i] = 0;
    __syncthreads();
    if (act) {
        #pragma unroll
        for (int h = 0; h < NH; ++h) {
            int b = 0;
            #pragma unroll
            for (int bb = 0; bb < BITS_; ++bb)
                if (acc[h * BITS_ + bb] > 0.f) b |= (1 << bb);
            atomicAdd(&hist[h * TS + b], 1);
        }
    }
    __syncthreads();
    for (int i = t; i < NH * TS; i += 256) {
        int v = hist[i];
        if (v) atomicAdd(&tallied[i], v);
    }
}

// ---------------- Kernel C: argmax, mask, compaction (1 block) ----------------
__global__ void kC(const int* __restrict__ tallied, const int* __restrict__ bucket_k,
                   const float* __restrict__ kern,
                   float* __restrict__ o_tallied, float* __restrict__ o_indices,
                   float* __restrict__ o_mask,
                   int* __restrict__ mask_i, int* __restrict__ mlist,
                   int* __restrict__ mtot, float* __restrict__ wC)
{
    const int t = threadIdx.x;
    __shared__ int s_idx[NH];
    __shared__ int s_mask[OCH];
    __shared__ int s_list[OCH];
    __shared__ int s_m;
    if (t < NH) {
        int best = tallied[t * TS];
        int bi = 0;
        for (int b = 1; b < TS; ++b) {
            int v = tallied[t * TS + b];
            if (v > best) { best = v; bi = b; }  // strict >  => first-max (jnp.argmax)
        }
        s_idx[t] = bi;
        o_indices[t] = (float)bi;
    }
    for (int i = t; i < NH * TS; i += 256) o_tallied[i] = (float)tallied[i];
    __syncthreads();
    // mask[k] = OR_{h',h} bucket_k[h'][k] == indices[h]
    int mk = 0;
    #pragma unroll
    for (int hp = 0; hp < NH; ++hp) {
        int b = bucket_k[hp * OCH + t];
        #pragma unroll
        for (int h = 0; h < NH; ++h) mk |= (b == s_idx[h]) ? 1 : 0;
    }
    s_mask[t] = mk;
    mask_i[t] = mk;
    o_mask[t] = (float)mk;
    __syncthreads();
    if (t == 0) {
        int m = 0;
        for (int k = 0; k < OCH; ++k) if (s_mask[k]) s_list[m++] = k;
        s_m = m;
        mtot[0] = m;
    }
    __syncthreads();
    const int m = s_m;
    if (t < m) {
        mlist[t] = s_list[t];
        const int oc = s_list[t];
        // compacted transposed weights: wC[(c*9+tap)*OCH + slot]
        for (int ct = 0; ct < DK; ++ct) wC[ct * OCH + t] = kern[oc * DK + ct];
    }
}

// ---------------- Kernel Z: zero-fill inactive output channels ----------------
__global__ void __launch_bounds__(256) kZ(float* __restrict__ out,
                                          const int* __restrict__ mask_i)
{
    const int b = blockIdx.x;
    const int oc = b & (OCH - 1);
    const int n = b >> 8;
    if (mask_i[oc]) return;
    float4* o = (float4*)(out + ((size_t)n * OCH + oc) * HW);
    for (int i = threadIdx.x; i < HW / 4; i += 256)
        o[i] = make_float4(0.f, 0.f, 0.f, 0.f);
}

// ---------------- Kernel D: main conv on active channels only ----------------
__global__ void __launch_bounds__(256) kD(const float* __restrict__ x,
        const float* __restrict__ wC, const int* __restrict__ mlist,
        const int* __restrict__ mtot, float* __restrict__ out)
{
    const int g = blockIdx.z;
    const int base = g * 16;
    const int m = mtot[0];
    if (base >= m) return;
    const int nslots = min(16, m - base);

    const int lane = threadIdx.x;
    const int ty = threadIdx.y;
    const int y = blockIdx.x * 4 + ty;
    const int n = blockIdx.y;
    const int xx = lane;
    const bool act = (xx < WW);

    float acc[16];
    #pragma unroll
    for (int s = 0; s < 16; ++s) acc[s] = 0.f;

    const float* xb = x + (size_t)n * CIN * HW;
    for (int c = 0; c < CIN; ++c) {
        const float* xc = xb + c * HW;
        float xv[9];
        #pragma unroll
        for (int ky = 0; ky < 3; ++ky) {
            int yy = y + ky - 1;
            bool vy = (yy >= 0) && (yy < HH);
            #pragma unroll
            for (int kx = 0; kx < 3; ++kx) {
                int x2 = xx + kx - 1;
                bool v = act && vy && (x2 >= 0) && (x2 < WW);
                xv[ky * 3 + kx] = v ? xc[yy * WW + x2] : 0.f;
            }
        }
        #pragma unroll
        for (int tap = 0; tap < 9; ++tap) {
            const float* wp = &wC[(c * 9 + tap) * OCH + base];  // uniform -> scalar loads
            #pragma unroll
            for (int s = 0; s < 16; ++s) acc[s] += xv[tap] * wp[s];
        }
    }
    if (act) {
        for (int s = 0; s < nslots; ++s) {
            int oc = mlist[base + s];
            out[((size_t)n * OCH + oc) * HW + y * WW + xx] = acc[s];
        }
    }
}

extern "C" void kernel_launch(void* const* d_in, const int* in_sizes, int n_in,
                              void* d_out, int out_size, void* d_ws, size_t ws_size,
                              hipStream_t stream)
{
    const float* x    = (const float*)d_in[0];
    const float* kern = (const float*)d_in[1];
    const float* a    = (const float*)d_in[2];

    float* out       = (float*)d_out;
    float* o_tallied = out + (size_t)NN * OCH * HW;   // 25,690,112
    float* o_indices = o_tallied + NH * TS;           // +512
    float* o_mask    = o_indices + NH;                // +8

    // workspace layout (~700 KB)
    float* aT  = (float*)d_ws;            // DPM*NB
    float* tcw = aT + DPM * NB;           // 9*NB
    float* wC  = tcw + 9 * NB;            // DK*OCH
    int* bucket_k = (int*)(wC + DK * OCH);// NH*OCH
    int* tallied  = bucket_k + NH * OCH;  // NH*TS
    int* mask_i   = tallied + NH * TS;    // OCH
    int* mlist    = mask_i + OCH;         // OCH
    int* mtot     = mlist + OCH;          // 1

    kA<<<1, 256, 0, stream>>>(kern, a, aT, tcw, bucket_k, tallied);
    kB<<<dim3(14, NN), dim3(64, 4), 0, stream>>>(x, aT, tcw, tallied);
    kC<<<1, 256, 0, stream>>>(tallied, bucket_k, kern, o_tallied, o_indices, o_mask,
                              mask_i, mlist, mtot, wC);
    kZ<<<NN * OCH, 256, 0, stream>>>(out, mask_i);
    kD<<<dim3(14, NN, 16), dim3(64, 4), 0, stream>>>(x, wC, mlist, mtot, out);
}

// Round 2
// 539.847 us; speedup vs baseline: 1.6406x; 1.6406x over previous
//
#include <hip/hip_runtime.h>
#include <math.h>

#define NH 8
#define BITS_ 5
#define NB 40
#define TS 64
#define MAUG 27
#define CIN 64
#define HH 56
#define WW 56
#define NN 32
#define OCH 256
#define DK 576
#define DPM 603
#define HW (HH*WW)

typedef __attribute__((ext_vector_type(8))) short short8;
typedef __attribute__((ext_vector_type(4))) float f32x4;
typedef union { uint4 u; short8 s; } frag_u;

__device__ __forceinline__ unsigned int bf16_rne(float v) {
    unsigned int u = __float_as_uint(v);
    return (u + 0x7fffu + ((u >> 16) & 1u)) >> 16;
}

// ---------------- kA1: prep (transpose a, tcw, zero tallied, scale) ----------------
__global__ void kA1(const float* __restrict__ kern, const float* __restrict__ a,
                    float* __restrict__ aT, float* __restrict__ tcw,
                    int* __restrict__ tallied, float* __restrict__ scale)
{
    const int t = threadIdx.x;
    const int g = blockIdx.x * 256 + t;
    for (int idx = g; idx < DPM * NB; idx += 32 * 256) {
        int d = idx / NB, j = idx - d * NB;
        aT[idx] = a[j * DPM + d];
    }
    if (g < 9 * NB) {
        int tap = g / NB, j = g - tap * NB;
        tcw[g] = 0.5f * (a[j * DPM + DK + tap] + a[j * DPM + DK + 9 + tap] +
                         a[j * DPM + DK + 18 + tap]);
    }
    if (g < NH * TS) tallied[g] = 0;

    if (blockIdx.x == 0) {
        __shared__ float s_red[256];
        const float4* kr = (const float4*)(kern + t * DK);
        float sq = 0.f;
        for (int i = 0; i < DK / 4; ++i) {
            float4 v = kr[i];
            sq += v.x * v.x + v.y * v.y + v.z * v.z + v.w * v.w;
        }
        s_red[t] = sq;
        __syncthreads();
        for (int s = 128; s > 0; s >>= 1) {
            if (t < s) s_red[t] = fmaxf(s_red[t], s_red[t + s]);
            __syncthreads();
        }
        if (t == 0) scale[0] = 0.83f / sqrtf(s_red[0]);
    }
}

// ---------------- kA2: hash kernel vectors (D-split across ty) ----------------
__global__ void __launch_bounds__(256) kA2(const float* __restrict__ kern,
        const float* __restrict__ aT, const float* __restrict__ scale,
        int* __restrict__ bucket_k)
{
    const int lane = threadIdx.x;        // 0..63
    const int ty = threadIdx.y;          // 0..3
    const int oc = blockIdx.x * 64 + lane;
    const float s = scale[0];

    float acc[NB];
    #pragma unroll
    for (int j = 0; j < NB; ++j) acc[j] = 0.f;
    float sq = 0.f;
    const int d0 = ty * 144;
    for (int d = d0; d < d0 + 144; ++d) {
        float xv = s * kern[oc * DK + d];
        sq += xv * xv;
        const float* wp = &aT[d * NB];
        #pragma unroll
        for (int j = 0; j < NB; ++j) acc[j] += xv * wp[j];
    }
    __shared__ float red[3 * 41 * 64];
    if (ty > 0) {
        #pragma unroll
        for (int j = 0; j < NB; ++j) red[((ty - 1) * 41 + j) * 64 + lane] = acc[j];
        red[((ty - 1) * 41 + 40) * 64 + lane] = sq;
    }
    __syncthreads();
    if (ty == 0) {
        #pragma unroll
        for (int j = 0; j < NB; ++j)
            acc[j] += red[j * 64 + lane] + red[(41 + j) * 64 + lane] + red[(82 + j) * 64 + lane];
        sq += red[40 * 64 + lane] + red[(41 + 40) * 64 + lane] + red[(82 + 40) * 64 + lane];
        float pv = sq;
        for (int m = 0; m < MAUG; ++m) {
            const float* wp = &aT[(DK + m) * NB];
            #pragma unroll
            for (int j = 0; j < NB; ++j) acc[j] += pv * wp[j];
            pv = pv * pv;
        }
        #pragma unroll
        for (int h = 0; h < NH; ++h) {
            int b = 0;
            #pragma unroll
            for (int bb = 0; bb < BITS_; ++bb)
                if (acc[h * BITS_ + bb] > 0.f) b |= (1 << bb);
            bucket_k[h * OCH + oc] = b & (TS - 1);
        }
    }
}

// ---------------- kB: vote conv, channel-split across ty ----------------
__global__ void __launch_bounds__(256) kB(const float* __restrict__ x,
        const float* __restrict__ aT, const float* __restrict__ tcw,
        int* __restrict__ tallied)
{
    const int lane = threadIdx.x;        // col
    const int ty = threadIdx.y;          // channel group
    const int y = blockIdx.x;
    const int n = blockIdx.y;
    const bool act = (lane < WW);

    float acc[NB];
    #pragma unroll
    for (int j = 0; j < NB; ++j) acc[j] = 0.f;

    __shared__ float red[3 * NB * 64];
    __shared__ int hist[NH * TS];
    const int t = ty * 64 + lane;
    for (int i = t; i < NH * TS; i += 256) hist[i] = 0;

    if (act) {
        const float* xb = x + (size_t)n * CIN * HW;
        const int c0 = ty * 16;
        for (int c = c0; c < c0 + 16; ++c) {
            const float* xc = xb + c * HW;
            float xv[9];
            #pragma unroll
            for (int ky = 0; ky < 3; ++ky) {
                int yy = y + ky - 1;
                bool vy = (yy >= 0) && (yy < HH);
                #pragma unroll
                for (int kx = 0; kx < 3; ++kx) {
                    int x2 = lane + kx - 1;
                    xv[ky * 3 + kx] = (vy && x2 >= 0 && x2 < WW) ? xc[yy * WW + x2] : 0.f;
                }
            }
            #pragma unroll
            for (int tap = 0; tap < 9; ++tap) {
                const float* wp = &aT[(c * 9 + tap) * NB];
                #pragma unroll
                for (int j = 0; j < NB; ++j) acc[j] += xv[tap] * wp[j];
            }
        }
    }
    if (ty > 0) {
        #pragma unroll
        for (int j = 0; j < NB; ++j) red[((ty - 1) * NB + j) * 64 + lane] = acc[j];
    }
    __syncthreads();
    if (ty == 0 && act) {
        #pragma unroll
        for (int j = 0; j < NB; ++j)
            acc[j] += red[j * 64 + lane] + red[(NB + j) * 64 + lane] + red[(2 * NB + j) * 64 + lane];
        #pragma unroll
        for (int tap = 0; tap < 9; ++tap) {
            int ky = tap / 3, kx = tap - ky * 3;
            int yy = y + ky - 1, x2 = lane + kx - 1;
            if (yy >= 0 && yy < HH && x2 >= 0 && x2 < WW) {
                const float* wp = &tcw[tap * NB];
                #pragma unroll
                for (int j = 0; j < NB; ++j) acc[j] += wp[j];
            }
        }
        #pragma unroll
        for (int h = 0; h < NH; ++h) {
            int b = 0;
            #pragma unroll
            for (int bb = 0; bb < BITS_; ++bb)
                if (acc[h * BITS_ + bb] > 0.f) b |= (1 << bb);
            atomicAdd(&hist[h * TS + b], 1);
        }
    }
    __syncthreads();
    for (int i = t; i < NH * TS; i += 256) {
        int v = hist[i];
        if (v) atomicAdd(&tallied[i], v);
    }
}

// ---------------- kW: pack weights into MFMA A-fragments (hi/lo bf16) ----------------
// frag f = kidxG*16 + mfrag, kidxG = cchunk*9 + tap (cchunk 0..1, tap 0..8)
// lane: oc = mfrag*16 + (lane&15); k = (lane>>4)*8 + j -> c = cchunk*32 + k
__global__ void kW(const float* __restrict__ kern, unsigned short* __restrict__ whA,
                   unsigned short* __restrict__ wlA)
{
    const int f = blockIdx.x;            // 0..287
    const int lane = threadIdx.x;        // 0..63
    const int kidxG = f >> 4, mf = f & 15;
    const int tap = kidxG % 9, cc = kidxG / 9;
    const int oc = mf * 16 + (lane & 15);
    const int cbase = cc * 32 + (lane >> 4) * 8;
    unsigned int hs[8], ls[8];
    #pragma unroll
    for (int j = 0; j < 8; ++j) {
        int c = cbase + j;
        float w = kern[oc * DK + c * 9 + tap];
        unsigned int h = bf16_rne(w);
        float hf = __uint_as_float(h << 16);
        unsigned int l = bf16_rne(w - hf);
        hs[j] = h; ls[j] = l;
    }
    unsigned int* ph = (unsigned int*)(whA + ((size_t)f * 64 + lane) * 8);
    unsigned int* pl = (unsigned int*)(wlA + ((size_t)f * 64 + lane) * 8);
    #pragma unroll
    for (int w2 = 0; w2 < 4; ++w2) {
        ph[w2] = (hs[2 * w2 + 1] << 16) | hs[2 * w2];
        pl[w2] = (ls[2 * w2 + 1] << 16) | ls[2 * w2];
    }
}

// ---------------- kC: argmax, mask, small outputs ----------------
__global__ void kC(const int* __restrict__ tallied, const int* __restrict__ bucket_k,
                   float* __restrict__ o_tallied, float* __restrict__ o_indices,
                   float* __restrict__ o_mask, float* __restrict__ maskF)
{
    const int t = threadIdx.x;
    __shared__ int s_idx[NH];
    if (t < NH) {
        int best = tallied[t * TS];
        int bi = 0;
        for (int b = 1; b < TS; ++b) {
            int v = tallied[t * TS + b];
            if (v > best) { best = v; bi = b; }
        }
        s_idx[t] = bi;
        o_indices[t] = (float)bi;
    }
    for (int i = t; i < NH * TS; i += 256) o_tallied[i] = (float)tallied[i];
    __syncthreads();
    int mk = 0;
    #pragma unroll
    for (int hp = 0; hp < NH; ++hp) {
        int b = bucket_k[hp * OCH + t];
        #pragma unroll
        for (int h = 0; h < NH; ++h) mk |= (b == s_idx[h]) ? 1 : 0;
    }
    maskF[t] = (float)mk;
    o_mask[t] = (float)mk;
}

// ---------------- kD: MFMA implicit-GEMM conv (bf16 3-term split) ----------------
// block: 512 thr = 8 waves (mg=wid&3 -> oc group of 64, ng=wid>>2 -> px row group)
// tile: 256 oc x 128 px (2 rows x 64-padded cols); K: 2 cchunks x 9 taps x 32 ch
__global__ void __launch_bounds__(512) kD(const float* __restrict__ x,
        const unsigned short* __restrict__ whA, const unsigned short* __restrict__ wlA,
        const float* __restrict__ maskF, float* __restrict__ out)
{
    __shared__ unsigned int lds[32 * 273];   // [c][r*68 + 1+col], packed (lo16<<16)|hi16
    const int lane = threadIdx.x;
    const int wid = threadIdx.y;
    const int y0 = blockIdx.x * 2;
    const int n = blockIdx.y;
    const int mg = wid & 3, ng = wid >> 2;
    const int lcol = lane & 15;
    const int crow = (lane >> 4) * 8 * 273;

    f32x4 acc[4][4];
    #pragma unroll
    for (int mf = 0; mf < 4; ++mf)
        #pragma unroll
        for (int nf = 0; nf < 4; ++nf)
            acc[mf][nf] = (f32x4){0.f, 0.f, 0.f, 0.f};

    const int t = wid * 64 + lane;
    const int colc = t & 63, grp = t >> 6;

    for (int cc = 0; cc < 2; ++cc) {
        __syncthreads();
        // zero pad entries (col 0 and 57..67 per (c,r))
        for (int i = t; i < 32 * 4 * 12; i += 512) {
            int c = i / 48, rem = i % 48;
            int r = rem / 12, o = rem % 12;
            lds[c * 273 + r * 68 + (o == 0 ? 0 : 56 + o)] = 0u;
        }
        // stage x rows y0-1..y0+2 for 32 channels, split to bf16 hi/lo packed
        if (colc < WW) {
            for (int pr = grp; pr < 128; pr += 8) {
                int c = pr >> 2, r = pr & 3;
                int y = y0 - 1 + r;
                float v = 0.f;
                if (y >= 0 && y < HH)
                    v = x[(((size_t)n * CIN + cc * 32 + c) * HH + y) * WW + colc];
                unsigned int h = bf16_rne(v);
                float hf = __uint_as_float(h << 16);
                unsigned int l = bf16_rne(v - hf);
                lds[c * 273 + r * 68 + 1 + colc] = (l << 16) | h;
            }
        }
        __syncthreads();

        #pragma unroll
        for (int tap = 0; tap < 9; ++tap) {
            const int ky = tap / 3, kx = tap - ky * 3;
            const int kidxG = cc * 9 + tap;
            // A fragments (weights) for this wave's 4 m-frags
            frag_u ah[4], al[4];
            #pragma unroll
            for (int mf = 0; mf < 4; ++mf) {
                size_t fi = (size_t)(kidxG * 16 + mg * 4 + mf) * 64 + lane;
                ah[mf].u = *(const uint4*)(whA + fi * 8);
                al[mf].u = *(const uint4*)(wlA + fi * 8);
            }
            #pragma unroll
            for (int nf = 0; nf < 4; ++nf) {
                const int base = crow + (ng + ky) * 68 + nf * 16 + lcol + kx;
                unsigned int q0 = lds[base];
                unsigned int q1 = lds[base + 273];
                unsigned int q2 = lds[base + 2 * 273];
                unsigned int q3 = lds[base + 3 * 273];
                unsigned int q4 = lds[base + 4 * 273];
                unsigned int q5 = lds[base + 5 * 273];
                unsigned int q6 = lds[base + 6 * 273];
                unsigned int q7 = lds[base + 7 * 273];
                frag_u bh, bl;
                bh.u.x = (q1 << 16) | (q0 & 0xffffu);
                bh.u.y = (q3 << 16) | (q2 & 0xffffu);
                bh.u.z = (q5 << 16) | (q4 & 0xffffu);
                bh.u.w = (q7 << 16) | (q6 & 0xffffu);
                bl.u.x = (q0 >> 16) | (q1 & 0xffff0000u);
                bl.u.y = (q2 >> 16) | (q3 & 0xffff0000u);
                bl.u.z = (q4 >> 16) | (q5 & 0xffff0000u);
                bl.u.w = (q6 >> 16) | (q7 & 0xffff0000u);
                #pragma unroll
                for (int mf = 0; mf < 4; ++mf) {
                    acc[mf][nf] = __builtin_amdgcn_mfma_f32_16x16x32_bf16(ah[mf].s, bh.s, acc[mf][nf], 0, 0, 0);
                    acc[mf][nf] = __builtin_amdgcn_mfma_f32_16x16x32_bf16(al[mf].s, bh.s, acc[mf][nf], 0, 0, 0);
                    acc[mf][nf] = __builtin_amdgcn_mfma_f32_16x16x32_bf16(ah[mf].s, bl.s, acc[mf][nf], 0, 0, 0);
                }
            }
        }
    }
    // epilogue: out[n][oc][y0+ng][col] = acc * mask[oc]
    const int yrow = y0 + ng;
    #pragma unroll
    for (int mf = 0; mf < 4; ++mf) {
        #pragma unroll
        for (int reg = 0; reg < 4; ++reg) {
            const int oc = mg * 64 + mf * 16 + (lane >> 4) * 4 + reg;
            const float mv = maskF[oc];
            float* ob = out + (((size_t)n * OCH + oc) * HH + yrow) * WW;
            #pragma unroll
            for (int nf = 0; nf < 4; ++nf) {
                int col = nf * 16 + lcol;
                if (col < WW) ob[col] = acc[mf][nf][reg] * mv;
            }
        }
    }
}

extern "C" void kernel_launch(void* const* d_in, const int* in_sizes, int n_in,
                              void* d_out, int out_size, void* d_ws, size_t ws_size,
                              hipStream_t stream)
{
    const float* x    = (const float*)d_in[0];
    const float* kern = (const float*)d_in[1];
    const float* a    = (const float*)d_in[2];

    float* out       = (float*)d_out;
    float* o_tallied = out + (size_t)NN * OCH * HW;
    float* o_indices = o_tallied + NH * TS;
    float* o_mask    = o_indices + NH;

    float* ws = (float*)d_ws;
    float* aT     = ws;                      // 24120 -> pad 24320
    float* tcw    = ws + 24320;              // 360   -> 24704
    float* scale  = ws + 24704;              // 1
    float* maskF  = ws + 24708;              // 256
    int*   bucket_k = (int*)(ws + 24968);    // 2048
    int*   tallied  = (int*)(ws + 27016);    // 512
    unsigned short* whA = (unsigned short*)(ws + 27536);   // 147456 ushorts
    unsigned short* wlA = (unsigned short*)((char*)whA + 294912);

    kA1<<<32, 256, 0, stream>>>(kern, a, aT, tcw, tallied, scale);
    kA2<<<4, dim3(64, 4), 0, stream>>>(kern, aT, scale, bucket_k);
    kB<<<dim3(HH, NN), dim3(64, 4), 0, stream>>>(x, aT, tcw, tallied);
    kW<<<288, 64, 0, stream>>>(kern, whA, wlA);
    kC<<<1, 256, 0, stream>>>(tallied, bucket_k, o_tallied, o_indices, o_mask, maskF);
    kD<<<dim3(28, NN), dim3(64, 8), 0, stream>>>(x, whA, wlA, maskF, out);
}

// Round 3
// 262.176 us; speedup vs baseline: 3.3781x; 2.0591x over previous
//
#include <hip/hip_runtime.h>
#include <math.h>

#define NH 8
#define BITS_ 5
#define NB 40
#define TS 64
#define MAUG 27
#define CIN 64
#define HH 56
#define WW 56
#define NN 32
#define OCH 256
#define DK 576
#define DPM 603
#define HW (HH*WW)

#define PITCH 20            // dwords per (r,L) cell: 4 used 16B units + 16B pad = 80B
#define TILE_DW 5440        // 4 rows * 68 cols * PITCH

typedef __attribute__((ext_vector_type(8))) short short8;
typedef __attribute__((ext_vector_type(4))) float f32x4;
typedef union { uint4 u; short8 s; } frag_u;

__device__ __forceinline__ unsigned int bf16_rne(float v) {
    unsigned int u = __float_as_uint(v);
    return (u + 0x7fffu + ((u >> 16) & 1u)) >> 16;
}

// Stage one 32-channel chunk of x (4 rows y0-1..y0+2, cols -1..66, split hi/lo bf16)
// into smem[0..TILE_DW) (hi) and smem[TILE_DW..2*TILE_DW) (lo). 512 threads.
// Layout: 16B unit (r, L, b) at dword (r*68+L)*PITCH + b*4 holds channels 8b..8b+7
// (even channel in low half of each dword).
__device__ __forceinline__ void stage_tile(unsigned int* smem, const float* __restrict__ x,
                                           int n, int cc, int y0, int t)
{
    const int q = t & 63;            // LDS col L = q+1
    const int rc = t >> 6;           // 0..7
    const int r = rc >> 1, half = rc & 1;
    const int y = y0 - 1 + r;
    const bool valid = (q < WW) && (y >= 0) && (y < HH);
    const float* xb = x + (((size_t)n * CIN + cc * 32 + half * 16) * HH + (y >= 0 ? (y < HH ? y : HH - 1) : 0)) * WW + q;

    unsigned int hs[16], ls[16];
    #pragma unroll
    for (int i = 0; i < 16; ++i) {
        float v = valid ? xb[(size_t)i * HW] : 0.f;
        unsigned int h = bf16_rne(v);
        float hf = __uint_as_float(h << 16);
        unsigned int l = bf16_rne(v - hf);
        hs[i] = h; ls[i] = l;
    }
    const int base = (r * 68 + (q + 1)) * PITCH + half * 8;
    #pragma unroll
    for (int ui = 0; ui < 2; ++ui) {
        uint4 uh, ul;
        uh.x = (hs[ui*8+1] << 16) | hs[ui*8+0];
        uh.y = (hs[ui*8+3] << 16) | hs[ui*8+2];
        uh.z = (hs[ui*8+5] << 16) | hs[ui*8+4];
        uh.w = (hs[ui*8+7] << 16) | hs[ui*8+6];
        ul.x = (ls[ui*8+1] << 16) | ls[ui*8+0];
        ul.y = (ls[ui*8+3] << 16) | ls[ui*8+2];
        ul.z = (ls[ui*8+5] << 16) | ls[ui*8+4];
        ul.w = (ls[ui*8+7] << 16) | ls[ui*8+6];
        *(uint4*)&smem[base + ui * 4] = uh;
        *(uint4*)&smem[TILE_DW + base + ui * 4] = ul;
    }
}

__device__ __forceinline__ void pad_fill(unsigned int* smem, int t)
{
    if (t < 128) {
        int b = t & 3, tile = (t >> 2) & 1, li = (t >> 3) & 3, r = (t >> 5) & 3;
        int L = (li == 0) ? 0 : 64 + li;
        int addr = tile * TILE_DW + (r * 68 + L) * PITCH + b * 4;
        *(uint4*)&smem[addr] = make_uint4(0u, 0u, 0u, 0u);
    }
}

// ---------------- kA1: prep (transpose a, ctab, zero tallied, scale) ----------------
__global__ void kA1(const float* __restrict__ kern, const float* __restrict__ a,
                    float* __restrict__ aT, float* __restrict__ ctab,
                    int* __restrict__ tallied, float* __restrict__ scale)
{
    const int t = threadIdx.x;
    const int g = blockIdx.x * 256 + t;
    for (int idx = g; idx < DPM * NB; idx += 32 * 256) {
        int d = idx / NB, j = idx - d * NB;
        aT[idx] = a[j * DPM + d];
    }
    // border-pattern constant table: ctab[pat][j], pat = ry*3+rx
    if (g < 9 * NB) {
        int pat = g / NB, j = g - pat * NB;
        int ry = pat / 3, rx = pat % 3;
        float s = 0.f;
        for (int ky = 0; ky < 3; ++ky) {
            if (ry == 0 && ky == 0) continue;
            if (ry == 2 && ky == 2) continue;
            for (int kx = 0; kx < 3; ++kx) {
                if (rx == 0 && kx == 0) continue;
                if (rx == 2 && kx == 2) continue;
                for (int mc = 0; mc < 3; ++mc)
                    s += a[j * DPM + DK + mc * 9 + ky * 3 + kx];
            }
        }
        ctab[g] = 0.5f * s;
    }
    if (g < NH * TS) tallied[g] = 0;

    if (blockIdx.x == 0) {
        __shared__ float s_red[256];
        const float4* kr = (const float4*)(kern + t * DK);
        float sq = 0.f;
        for (int i = 0; i < DK / 4; ++i) {
            float4 v = kr[i];
            sq += v.x * v.x + v.y * v.y + v.z * v.z + v.w * v.w;
        }
        s_red[t] = sq;
        __syncthreads();
        for (int s = 128; s > 0; s >>= 1) {
            if (t < s) s_red[t] = fmaxf(s_red[t], s_red[t + s]);
            __syncthreads();
        }
        if (t == 0) scale[0] = 0.83f / sqrtf(s_red[0]);
    }
}

// ---------------- kA2: hash kernel vectors (D-split across ty) ----------------
__global__ void __launch_bounds__(256) kA2(const float* __restrict__ kern,
        const float* __restrict__ aT, const float* __restrict__ scale,
        int* __restrict__ bucket_k)
{
    const int lane = threadIdx.x;
    const int ty = threadIdx.y;
    const int oc = blockIdx.x * 64 + lane;
    const float s = scale[0];

    float acc[NB];
    #pragma unroll
    for (int j = 0; j < NB; ++j) acc[j] = 0.f;
    float sq = 0.f;
    const int d0 = ty * 144;
    for (int d = d0; d < d0 + 144; ++d) {
        float xv = s * kern[oc * DK + d];
        sq += xv * xv;
        const float* wp = &aT[d * NB];
        #pragma unroll
        for (int j = 0; j < NB; ++j) acc[j] += xv * wp[j];
    }
    __shared__ float red[3 * 41 * 64];
    if (ty > 0) {
        #pragma unroll
        for (int j = 0; j < NB; ++j) red[((ty - 1) * 41 + j) * 64 + lane] = acc[j];
        red[((ty - 1) * 41 + 40) * 64 + lane] = sq;
    }
    __syncthreads();
    if (ty == 0) {
        #pragma unroll
        for (int j = 0; j < NB; ++j)
            acc[j] += red[j * 64 + lane] + red[(41 + j) * 64 + lane] + red[(82 + j) * 64 + lane];
        sq += red[40 * 64 + lane] + red[(41 + 40) * 64 + lane] + red[(82 + 40) * 64 + lane];
        float pv = sq;
        for (int m = 0; m < MAUG; ++m) {
            const float* wp = &aT[(DK + m) * NB];
            #pragma unroll
            for (int j = 0; j < NB; ++j) acc[j] += pv * wp[j];
            pv = pv * pv;
        }
        #pragma unroll
        for (int h = 0; h < NH; ++h) {
            int b = 0;
            #pragma unroll
            for (int bb = 0; bb < BITS_; ++bb)
                if (acc[h * BITS_ + bb] > 0.f) b |= (1 << bb);
            bucket_k[h * OCH + oc] = b & (TS - 1);
        }
    }
}

// ---------------- kW: pack A-fragments ----------------
// blocks 0..287: main conv weights (hi/lo bf16), frag f = kidxG*16+mf
// blocks 288..341: vote weights (3-way bf16 split), frag fv = kidxG*3+mf
__global__ void kW(const float* __restrict__ kern, const float* __restrict__ a,
                   unsigned short* __restrict__ whA, unsigned short* __restrict__ wlA,
                   unsigned short* __restrict__ va0, unsigned short* __restrict__ va1,
                   unsigned short* __restrict__ va2)
{
    const int f = blockIdx.x;
    const int lane = threadIdx.x;
    if (f < 288) {
        const int kidxG = f >> 4, mf = f & 15;
        const int tap = kidxG % 9, cc = kidxG / 9;
        const int oc = mf * 16 + (lane & 15);
        const int cbase = cc * 32 + (lane >> 4) * 8;
        unsigned int hs[8], ls[8];
        #pragma unroll
        for (int j = 0; j < 8; ++j) {
            float w = kern[oc * DK + (cbase + j) * 9 + tap];
            unsigned int h = bf16_rne(w);
            float hf = __uint_as_float(h << 16);
            unsigned int l = bf16_rne(w - hf);
            hs[j] = h; ls[j] = l;
        }
        unsigned int* ph = (unsigned int*)(whA + ((size_t)f * 64 + lane) * 8);
        unsigned int* pl = (unsigned int*)(wlA + ((size_t)f * 64 + lane) * 8);
        #pragma unroll
        for (int w2 = 0; w2 < 4; ++w2) {
            ph[w2] = (hs[2 * w2 + 1] << 16) | hs[2 * w2];
            pl[w2] = (ls[2 * w2 + 1] << 16) | ls[2 * w2];
        }
    } else {
        const int fv = f - 288;
        const int kidxG = fv / 3, mf = fv % 3;
        const int tap = kidxG % 9, cc = kidxG / 9;
        const int j = mf * 16 + (lane & 15);
        const int cbase = cc * 32 + (lane >> 4) * 8;
        unsigned int v0[8], v1[8], v2[8];
        #pragma unroll
        for (int jj = 0; jj < 8; ++jj) {
            float w = (j < NB) ? a[j * DPM + (cbase + jj) * 9 + tap] : 0.f;
            unsigned int a0 = bf16_rne(w);
            float r1 = w - __uint_as_float(a0 << 16);
            unsigned int a1 = bf16_rne(r1);
            float r2 = r1 - __uint_as_float(a1 << 16);
            unsigned int a2 = bf16_rne(r2);
            v0[jj] = a0; v1[jj] = a1; v2[jj] = a2;
        }
        unsigned int* p0 = (unsigned int*)(va0 + ((size_t)fv * 64 + lane) * 8);
        unsigned int* p1 = (unsigned int*)(va1 + ((size_t)fv * 64 + lane) * 8);
        unsigned int* p2 = (unsigned int*)(va2 + ((size_t)fv * 64 + lane) * 8);
        #pragma unroll
        for (int w2 = 0; w2 < 4; ++w2) {
            p0[w2] = (v0[2 * w2 + 1] << 16) | v0[2 * w2];
            p1[w2] = (v1[2 * w2 + 1] << 16) | v1[2 * w2];
            p2[w2] = (v2[2 * w2 + 1] << 16) | v2[2 * w2];
        }
    }
}

// ---------------- kBm: MFMA vote conv + bits + histogram ----------------
// grid (28, 32), block (64,8). wave wid: ng = wid&1 (row), nfg = wid>>1 (16-px group).
// 5-product split: w0x0, w0x1, w1x0, w1x1, w2x0.
__global__ void __launch_bounds__(512) kBm(const float* __restrict__ x,
        const unsigned short* __restrict__ va0, const unsigned short* __restrict__ va1,
        const unsigned short* __restrict__ va2, const float* __restrict__ ctab,
        int* __restrict__ tallied)
{
    __shared__ unsigned int smem[2 * TILE_DW + 512];
    int* hist = (int*)&smem[2 * TILE_DW];
    const int lane = threadIdx.x, wid = threadIdx.y;
    const int y0 = blockIdx.x * 2, n = blockIdx.y;
    const int ng = wid & 1, nfg = wid >> 1;
    const int lcol = lane & 15, hi = lane >> 4;
    const int t = wid * 64 + lane;

    f32x4 acc[3];
    #pragma unroll
    for (int mf = 0; mf < 3; ++mf) acc[mf] = (f32x4){0.f, 0.f, 0.f, 0.f};

    pad_fill(smem, t);
    for (int i = t; i < NH * TS; i += 512) hist[i] = 0;

    for (int cc = 0; cc < 2; ++cc) {
        __syncthreads();
        stage_tile(smem, x, n, cc, y0, t);
        __syncthreads();
        #pragma unroll
        for (int tap = 0; tap < 9; ++tap) {
            const int ky = tap / 3, kx = tap - ky * 3;
            frag_u a0[3], a1[3], a2[3];
            #pragma unroll
            for (int mf = 0; mf < 3; ++mf) {
                size_t fi = ((size_t)((cc * 9 + tap) * 3 + mf) * 64 + lane) * 8;
                a0[mf].u = *(const uint4*)(va0 + fi);
                a1[mf].u = *(const uint4*)(va1 + fi);
                a2[mf].u = *(const uint4*)(va2 + fi);
            }
            const int R = (ng + ky) * 68 + nfg * 16 + lcol + kx;
            const int ad = R * PITCH + hi * 4;
            frag_u b0, b1;
            b0.u = *(const uint4*)&smem[ad];
            b1.u = *(const uint4*)&smem[ad + TILE_DW];
            #pragma unroll
            for (int mf = 0; mf < 3; ++mf) {
                acc[mf] = __builtin_amdgcn_mfma_f32_16x16x32_bf16(a0[mf].s, b0.s, acc[mf], 0, 0, 0);
                acc[mf] = __builtin_amdgcn_mfma_f32_16x16x32_bf16(a0[mf].s, b1.s, acc[mf], 0, 0, 0);
                acc[mf] = __builtin_amdgcn_mfma_f32_16x16x32_bf16(a1[mf].s, b0.s, acc[mf], 0, 0, 0);
                acc[mf] = __builtin_amdgcn_mfma_f32_16x16x32_bf16(a1[mf].s, b1.s, acc[mf], 0, 0, 0);
                acc[mf] = __builtin_amdgcn_mfma_f32_16x16x32_bf16(a2[mf].s, b0.s, acc[mf], 0, 0, 0);
            }
        }
    }
    __syncthreads();
    // transpose C-frags into projT[row*64+px][j] (stride 49)
    float* projT = (float*)smem;
    const int px = nfg * 16 + lcol;
    #pragma unroll
    for (int mf = 0; mf < 3; ++mf) {
        #pragma unroll
        for (int reg = 0; reg < 4; ++reg) {
            int j = mf * 16 + hi * 4 + reg;
            projT[(ng * 64 + px) * 49 + j] = acc[mf][reg];
        }
    }
    __syncthreads();
    if (t < 2 * WW) {
        const int row = t / WW, pxx = t - row * WW;
        const int y = y0 + row;
        const int ry = (y == 0) ? 0 : ((y == HH - 1) ? 2 : 1);
        const int rx = (pxx == 0) ? 0 : ((pxx == WW - 1) ? 2 : 1);
        const float* ct = ctab + (ry * 3 + rx) * NB;
        const float* pr = projT + (row * 64 + pxx) * 49;
        #pragma unroll
        for (int h = 0; h < NH; ++h) {
            int b = 0;
            #pragma unroll
            for (int bb = 0; bb < BITS_; ++bb)
                if (pr[h * BITS_ + bb] + ct[h * BITS_ + bb] > 0.f) b |= (1 << bb);
            atomicAdd(&hist[h * TS + (b & (TS - 1))], 1);
        }
    }
    __syncthreads();
    for (int i = t; i < NH * TS; i += 512) {
        int v = hist[i];
        if (v) atomicAdd(&tallied[i], v);
    }
}

// ---------------- kC: argmax, mask, small outputs ----------------
__global__ void kC(const int* __restrict__ tallied, const int* __restrict__ bucket_k,
                   float* __restrict__ o_tallied, float* __restrict__ o_indices,
                   float* __restrict__ o_mask, float* __restrict__ maskF)
{
    const int t = threadIdx.x;
    __shared__ int s_idx[NH];
    if (t < NH) {
        int best = tallied[t * TS];
        int bi = 0;
        for (int b = 1; b < TS; ++b) {
            int v = tallied[t * TS + b];
            if (v > best) { best = v; bi = b; }
        }
        s_idx[t] = bi;
        o_indices[t] = (float)bi;
    }
    for (int i = t; i < NH * TS; i += 256) o_tallied[i] = (float)tallied[i];
    __syncthreads();
    int mk = 0;
    #pragma unroll
    for (int hp = 0; hp < NH; ++hp) {
        int b = bucket_k[hp * OCH + t];
        #pragma unroll
        for (int h = 0; h < NH; ++h) mk |= (b == s_idx[h]) ? 1 : 0;
    }
    maskF[t] = (float)mk;
    o_mask[t] = (float)mk;
}

// ---------------- kD: MFMA main conv (bf16 3-term split, b128 B-frags) ----------------
__global__ void __launch_bounds__(512) kD(const float* __restrict__ x,
        const unsigned short* __restrict__ whA, const unsigned short* __restrict__ wlA,
        const float* __restrict__ maskF, float* __restrict__ out)
{
    __shared__ unsigned int smem[2 * TILE_DW];
    const int lane = threadIdx.x, wid = threadIdx.y;
    const int y0 = blockIdx.x * 2, n = blockIdx.y;
    const int mg = wid & 3, ng = wid >> 2;
    const int lcol = lane & 15, hi = lane >> 4;
    const int t = wid * 64 + lane;

    f32x4 acc[4][4];
    #pragma unroll
    for (int mf = 0; mf < 4; ++mf)
        #pragma unroll
        for (int nf = 0; nf < 4; ++nf)
            acc[mf][nf] = (f32x4){0.f, 0.f, 0.f, 0.f};

    pad_fill(smem, t);

    for (int cc = 0; cc < 2; ++cc) {
        __syncthreads();
        stage_tile(smem, x, n, cc, y0, t);
        __syncthreads();
        #pragma unroll
        for (int tap = 0; tap < 9; ++tap) {
            const int ky = tap / 3, kx = tap - ky * 3;
            frag_u ah[4], al[4];
            #pragma unroll
            for (int mf = 0; mf < 4; ++mf) {
                size_t fi = ((size_t)((cc * 9 + tap) * 16 + mg * 4 + mf) * 64 + lane) * 8;
                ah[mf].u = *(const uint4*)(whA + fi);
                al[mf].u = *(const uint4*)(wlA + fi);
            }
            #pragma unroll
            for (int nf = 0; nf < 4; ++nf) {
                const int R = (ng + ky) * 68 + nf * 16 + lcol + kx;
                const int ad = R * PITCH + hi * 4;
                frag_u bh, bl;
                bh.u = *(const uint4*)&smem[ad];
                bl.u = *(const uint4*)&smem[ad + TILE_DW];
                #pragma unroll
                for (int mf = 0; mf < 4; ++mf) {
                    acc[mf][nf] = __builtin_amdgcn_mfma_f32_16x16x32_bf16(ah[mf].s, bh.s, acc[mf][nf], 0, 0, 0);
                    acc[mf][nf] = __builtin_amdgcn_mfma_f32_16x16x32_bf16(al[mf].s, bh.s, acc[mf][nf], 0, 0, 0);
                    acc[mf][nf] = __builtin_amdgcn_mfma_f32_16x16x32_bf16(ah[mf].s, bl.s, acc[mf][nf], 0, 0, 0);
                }
            }
        }
    }
    const int yrow = y0 + ng;
    #pragma unroll
    for (int mf = 0; mf < 4; ++mf) {
        #pragma unroll
        for (int reg = 0; reg < 4; ++reg) {
            const int oc = mg * 64 + mf * 16 + hi * 4 + reg;
            const float mv = maskF[oc];
            float* ob = out + (((size_t)n * OCH + oc) * HH + yrow) * WW;
            #pragma unroll
            for (int nf = 0; nf < 4; ++nf) {
                int col = nf * 16 + lcol;
                if (col < WW) ob[col] = acc[mf][nf][reg] * mv;
            }
        }
    }
}

extern "C" void kernel_launch(void* const* d_in, const int* in_sizes, int n_in,
                              void* d_out, int out_size, void* d_ws, size_t ws_size,
                              hipStream_t stream)
{
    const float* x    = (const float*)d_in[0];
    const float* kern = (const float*)d_in[1];
    const float* a    = (const float*)d_in[2];

    float* out       = (float*)d_out;
    float* o_tallied = out + (size_t)NN * OCH * HW;
    float* o_indices = o_tallied + NH * TS;
    float* o_mask    = o_indices + NH;

    float* ws = (float*)d_ws;
    float* aT      = ws;                        // 24120 (pad 24320)
    float* scale   = ws + 24320;                // 1 (pad 64)
    float* ctab    = ws + 24384;                // 360 (pad 384)
    float* maskF   = ws + 24768;                // 256
    int*   bucket_k = (int*)(ws + 25024);       // 2048
    int*   tallied  = (int*)(ws + 27072);       // 512
    unsigned short* whA = (unsigned short*)(ws + 27584);    // 288*64*8 us
    unsigned short* wlA = (unsigned short*)(ws + 101312);
    unsigned short* va0 = (unsigned short*)(ws + 175040);   // 54*64*8 us
    unsigned short* va1 = (unsigned short*)(ws + 188864);
    unsigned short* va2 = (unsigned short*)(ws + 202688);

    kA1<<<32, 256, 0, stream>>>(kern, a, aT, ctab, tallied, scale);
    kA2<<<4, dim3(64, 4), 0, stream>>>(kern, aT, scale, bucket_k);
    kW<<<342, 64, 0, stream>>>(kern, a, whA, wlA, va0, va1, va2);
    kBm<<<dim3(28, NN), dim3(64, 8), 0, stream>>>(x, va0, va1, va2, ctab, tallied);
    kC<<<1, 256, 0, stream>>>(tallied, bucket_k, o_tallied, o_indices, o_mask, maskF);
    kD<<<dim3(28, NN), dim3(64, 8), 0, stream>>>(x, whA, wlA, maskF, out);
}

// Round 4
// 240.386 us; speedup vs baseline: 3.6843x; 1.0906x over previous
//
#include <hip/hip_runtime.h>
#include <math.h>

#define NH 8
#define BITS_ 5
#define NB 40
#define TS 64
#define MAUG 27
#define CIN 64
#define HH 56
#define WW 56
#define NN 32
#define OCH 256
#define DK 576
#define DPM 603
#define HW (HH*WW)

#define CPITCH 36           // dwords per (r,L) cell: 8x16B channel-units + 16B pad (bank stagger 4)
#define TILE_D 9792         // kD: 4 rows * 68 cols * 36
#define TILE_V 7344         // kV: 3 rows * 68 cols * 36

typedef __attribute__((ext_vector_type(4))) float f32x4;
typedef __attribute__((ext_vector_type(8))) _Float16 f16x8;
typedef union { uint4 u; f16x8 h; } fragh_u;

__device__ __forceinline__ unsigned int f16b(float v) {
    union { _Float16 h; unsigned short u; } cv;
    cv.h = (_Float16)v;
    return (unsigned int)cv.u;
}
__device__ __forceinline__ float f16tof(unsigned int b) {
    union { _Float16 h; unsigned short u; } cv;
    cv.u = (unsigned short)b;
    return (float)cv.h;
}

// ---------------- kA1: prep (transpose a, ctab, zero tallied, scale) ----------------
__global__ void kA1(const float* __restrict__ kern, const float* __restrict__ a,
                    float* __restrict__ aT, float* __restrict__ ctab,
                    int* __restrict__ tallied, float* __restrict__ scale)
{
    const int t = threadIdx.x;
    const int g = blockIdx.x * 256 + t;
    for (int idx = g; idx < DPM * NB; idx += 32 * 256) {
        int d = idx / NB, j = idx - d * NB;
        aT[idx] = a[j * DPM + d];
    }
    if (g < 9 * NB) {
        int pat = g / NB, j = g - pat * NB;
        int ry = pat / 3, rx = pat % 3;
        float s = 0.f;
        for (int ky = 0; ky < 3; ++ky) {
            if (ry == 0 && ky == 0) continue;
            if (ry == 2 && ky == 2) continue;
            for (int kx = 0; kx < 3; ++kx) {
                if (rx == 0 && kx == 0) continue;
                if (rx == 2 && kx == 2) continue;
                for (int mc = 0; mc < 3; ++mc)
                    s += a[j * DPM + DK + mc * 9 + ky * 3 + kx];
            }
        }
        ctab[g] = 0.5f * s;
    }
    if (g < NH * TS) tallied[g] = 0;

    if (blockIdx.x == 0) {
        __shared__ float s_red[256];
        const float4* kr = (const float4*)(kern + t * DK);
        float sq = 0.f;
        for (int i = 0; i < DK / 4; ++i) {
            float4 v = kr[i];
            sq += v.x * v.x + v.y * v.y + v.z * v.z + v.w * v.w;
        }
        s_red[t] = sq;
        __syncthreads();
        for (int s = 128; s > 0; s >>= 1) {
            if (t < s) s_red[t] = fmaxf(s_red[t], s_red[t + s]);
            __syncthreads();
        }
        if (t == 0) scale[0] = 0.83f / sqrtf(s_red[0]);
    }
}

// ---------------- kA2: hash kernel vectors (D-split across ty) ----------------
__global__ void __launch_bounds__(256) kA2(const float* __restrict__ kern,
        const float* __restrict__ aT, const float* __restrict__ scale,
        int* __restrict__ bucket_k)
{
    const int lane = threadIdx.x;
    const int ty = threadIdx.y;
    const int oc = blockIdx.x * 64 + lane;
    const float s = scale[0];

    float acc[NB];
    #pragma unroll
    for (int j = 0; j < NB; ++j) acc[j] = 0.f;
    float sq = 0.f;
    const int d0 = ty * 144;
    for (int d = d0; d < d0 + 144; ++d) {
        float xv = s * kern[oc * DK + d];
        sq += xv * xv;
        const float* wp = &aT[d * NB];
        #pragma unroll
        for (int j = 0; j < NB; ++j) acc[j] += xv * wp[j];
    }
    __shared__ float red[3 * 41 * 64];
    if (ty > 0) {
        #pragma unroll
        for (int j = 0; j < NB; ++j) red[((ty - 1) * 41 + j) * 64 + lane] = acc[j];
        red[((ty - 1) * 41 + 40) * 64 + lane] = sq;
    }
    __syncthreads();
    if (ty == 0) {
        #pragma unroll
        for (int j = 0; j < NB; ++j)
            acc[j] += red[j * 64 + lane] + red[(41 + j) * 64 + lane] + red[(82 + j) * 64 + lane];
        sq += red[40 * 64 + lane] + red[(41 + 40) * 64 + lane] + red[(82 + 40) * 64 + lane];
        float pv = sq;
        for (int m = 0; m < MAUG; ++m) {
            const float* wp = &aT[(DK + m) * NB];
            #pragma unroll
            for (int j = 0; j < NB; ++j) acc[j] += pv * wp[j];
            pv = pv * pv;
        }
        #pragma unroll
        for (int h = 0; h < NH; ++h) {
            int b = 0;
            #pragma unroll
            for (int bb = 0; bb < BITS_; ++bb)
                if (acc[h * BITS_ + bb] > 0.f) b |= (1 << bb);
            bucket_k[h * OCH + oc] = b & (TS - 1);
        }
    }
}

// ---------------- kW: pack A-fragments ----------------
// blocks 0..287: main conv weights (single f16), frag f = kidxG*16+mf
// blocks 288..341: vote weights (f16 hi/lo), frag fv = kidxG*3+mfv
__global__ void kW(const float* __restrict__ kern, const float* __restrict__ a,
                   unsigned short* __restrict__ whA,
                   unsigned short* __restrict__ vaH, unsigned short* __restrict__ vaL)
{
    const int f = blockIdx.x;
    const int lane = threadIdx.x;
    if (f < 288) {
        const int kidxG = f >> 4, mf = f & 15;
        const int tap = kidxG % 9, cc = kidxG / 9;
        const int oc = mf * 16 + (lane & 15);
        const int cbase = cc * 32 + (lane >> 4) * 8;
        unsigned int hs[8];
        #pragma unroll
        for (int j = 0; j < 8; ++j)
            hs[j] = f16b(kern[oc * DK + (cbase + j) * 9 + tap]);
        unsigned int* p = (unsigned int*)(whA + ((size_t)f * 64 + lane) * 8);
        #pragma unroll
        for (int w2 = 0; w2 < 4; ++w2)
            p[w2] = hs[2 * w2] | (hs[2 * w2 + 1] << 16);
    } else {
        const int fv = f - 288;
        const int kidxG = fv / 3, mfv = fv % 3;
        const int tap = kidxG % 9, cc = kidxG / 9;
        const int j = mfv * 16 + (lane & 15);
        const int cbase = cc * 32 + (lane >> 4) * 8;
        unsigned int hs[8], ls[8];
        #pragma unroll
        for (int jj = 0; jj < 8; ++jj) {
            float w = (j < NB) ? a[j * DPM + (cbase + jj) * 9 + tap] : 0.f;
            unsigned int h = f16b(w);
            unsigned int l = f16b(w - f16tof(h));
            hs[jj] = h; ls[jj] = l;
        }
        unsigned int* ph = (unsigned int*)(vaH + ((size_t)fv * 64 + lane) * 8);
        unsigned int* pl = (unsigned int*)(vaL + ((size_t)fv * 64 + lane) * 8);
        #pragma unroll
        for (int w2 = 0; w2 < 4; ++w2) {
            ph[w2] = hs[2 * w2] | (hs[2 * w2 + 1] << 16);
            pl[w2] = ls[2 * w2] | (ls[2 * w2 + 1] << 16);
        }
    }
}

// ---------------- kV: MFMA vote conv (f16 hi/lo 3-term) + bits + histogram ----------------
// grid (56, 32), block (64,8). 1 output row per block; 3 x-rows staged once.
// wave wid: nfg = wid&3 (16-px group); wid<4 handles mfv {0,2}, wid>=4 handles mfv {1}.
__global__ void __launch_bounds__(512) kV(const float* __restrict__ x,
        const unsigned short* __restrict__ vaH, const unsigned short* __restrict__ vaL,
        const float* __restrict__ ctab, int* __restrict__ tallied)
{
    __shared__ unsigned int smem[2 * TILE_V];
    const int lane = threadIdx.x, wid = threadIdx.y;
    const int y0 = blockIdx.x, n = blockIdx.y;
    const int lcol = lane & 15, hi = lane >> 4;
    const int t = wid * 64 + lane;
    const int nfg = wid & 3;
    const int nm = (wid < 4) ? 2 : 1;
    const int mfv0 = (wid < 4) ? 0 : 1;

    f32x4 accv[2];
    accv[0] = (f32x4){0.f, 0.f, 0.f, 0.f};
    accv[1] = (f32x4){0.f, 0.f, 0.f, 0.f};

    if (t < 192) {
        int li = t & 3, b = (t >> 2) & 7, rt = t >> 5;      // rt 0..5
        int r = rt % 3, tile = rt / 3;
        int L = (li == 0) ? 0 : 64 + li;
        *(uint4*)&smem[tile * TILE_V + (r * 68 + L) * CPITCH + b * 4] = make_uint4(0u, 0u, 0u, 0u);
    }
    {
        const int q = t & 63, rc = t >> 6;
        if (rc < 6) {
            const int r = rc >> 1, half = rc & 1;
            const int y = y0 - 1 + r;
            const bool valid = (q < WW) && (y >= 0) && (y < HH);
            const float* xb = x + (((size_t)n * CIN + half * 32) * HH + (valid ? y : 0)) * WW + q;
            const int base = (r * 68 + q + 1) * CPITCH + half * 16;
            #pragma unroll
            for (int u = 0; u < 4; ++u) {
                unsigned int dh[4], dl[4];
                #pragma unroll
                for (int dd = 0; dd < 4; ++dd) {
                    float v0 = valid ? xb[(size_t)(u * 8 + dd * 2) * HW] : 0.f;
                    float v1 = valid ? xb[(size_t)(u * 8 + dd * 2 + 1) * HW] : 0.f;
                    unsigned int h0 = f16b(v0), h1 = f16b(v1);
                    unsigned int l0 = f16b(v0 - f16tof(h0)), l1 = f16b(v1 - f16tof(h1));
                    dh[dd] = h0 | (h1 << 16);
                    dl[dd] = l0 | (l1 << 16);
                }
                *(uint4*)&smem[base + u * 4] = make_uint4(dh[0], dh[1], dh[2], dh[3]);
                *(uint4*)&smem[TILE_V + base + u * 4] = make_uint4(dl[0], dl[1], dl[2], dl[3]);
            }
        }
    }
    __syncthreads();

    for (int cc = 0; cc < 2; ++cc) {
        #pragma unroll
        for (int tap = 0; tap < 9; ++tap) {
            const int ky = tap / 3, kx = tap - ky * 3;
            const int R = ky * 68 + nfg * 16 + lcol + kx;
            const int ad = R * CPITCH + cc * 16 + hi * 4;
            fragh_u bh, bl;
            bh.u = *(const uint4*)&smem[ad];
            bl.u = *(const uint4*)&smem[TILE_V + ad];
            const int fvbase = (cc * 9 + tap) * 3;
            #pragma unroll
            for (int ci = 0; ci < 2; ++ci) {
                if (ci < nm) {
                    const int mfv = (ci == 0) ? mfv0 : 2;
                    fragh_u vh, vl;
                    size_t fi = ((size_t)(fvbase + mfv) * 64 + lane) * 8;
                    vh.u = *(const uint4*)(vaH + fi);
                    vl.u = *(const uint4*)(vaL + fi);
                    accv[ci] = __builtin_amdgcn_mfma_f32_16x16x32_f16(vh.h, bh.h, accv[ci], 0, 0, 0);
                    accv[ci] = __builtin_amdgcn_mfma_f32_16x16x32_f16(vh.h, bl.h, accv[ci], 0, 0, 0);
                    accv[ci] = __builtin_amdgcn_mfma_f32_16x16x32_f16(vl.h, bh.h, accv[ci], 0, 0, 0);
                }
            }
        }
    }
    __syncthreads();
    // overlay: projT[px][j] (stride 49) + hist in former xh tile
    float* projT = (float*)smem;
    int* hist = (int*)&smem[3200];
    const int px = nfg * 16 + lcol;
    #pragma unroll
    for (int ci = 0; ci < 2; ++ci) {
        if (ci < nm) {
            const int mfv = (ci == 0) ? mfv0 : 2;
            #pragma unroll
            for (int reg = 0; reg < 4; ++reg) {
                int j = mfv * 16 + hi * 4 + reg;
                projT[px * 49 + j] = accv[ci][reg];
            }
        }
    }
    for (int i = t; i < NH * TS; i += 512) hist[i] = 0;
    __syncthreads();
    if (t < WW) {
        const int ry = (y0 == 0) ? 0 : ((y0 == HH - 1) ? 2 : 1);
        const int rx = (t == 0) ? 0 : ((t == WW - 1) ? 2 : 1);
        const float* ct = ctab + (ry * 3 + rx) * NB;
        const float* pr = projT + t * 49;
        #pragma unroll
        for (int h = 0; h < NH; ++h) {
            int b = 0;
            #pragma unroll
            for (int bb = 0; bb < BITS_; ++bb)
                if (pr[h * BITS_ + bb] + ct[h * BITS_ + bb] > 0.f) b |= (1 << bb);
            atomicAdd(&hist[h * TS + (b & (TS - 1))], 1);
        }
    }
    __syncthreads();
    for (int i = t; i < NH * TS; i += 512) {
        int v = hist[i];
        if (v) atomicAdd(&tallied[i], v);
    }
}

// ---------------- kC: argmax, mask, small outputs ----------------
__global__ void kC(const int* __restrict__ tallied, const int* __restrict__ bucket_k,
                   float* __restrict__ o_tallied, float* __restrict__ o_indices,
                   float* __restrict__ o_mask, float* __restrict__ maskF)
{
    const int t = threadIdx.x;
    __shared__ int s_idx[NH];
    if (t < NH) {
        int best = tallied[t * TS];
        int bi = 0;
        for (int b = 1; b < TS; ++b) {
            int v = tallied[t * TS + b];
            if (v > best) { best = v; bi = b; }
        }
        s_idx[t] = bi;
        o_indices[t] = (float)bi;
    }
    for (int i = t; i < NH * TS; i += 256) o_tallied[i] = (float)tallied[i];
    __syncthreads();
    int mk = 0;
    #pragma unroll
    for (int hp = 0; hp < NH; ++hp) {
        int b = bucket_k[hp * OCH + t];
        #pragma unroll
        for (int h = 0; h < NH; ++h) mk |= (b == s_idx[h]) ? 1 : 0;
    }
    maskF[t] = (float)mk;
    o_mask[t] = (float)mk;
}

// ---------------- kD: MFMA main conv (single f16), stage-once, 1 barrier ----------------
__global__ void __launch_bounds__(512) kD(const float* __restrict__ x,
        const unsigned short* __restrict__ whA,
        const float* __restrict__ maskF, float* __restrict__ out)
{
    __shared__ unsigned int smem[TILE_D];
    const int lane = threadIdx.x, wid = threadIdx.y;
    const int y0 = blockIdx.x * 2, n = blockIdx.y;
    const int mg = wid & 3, ng = wid >> 2;
    const int lcol = lane & 15, hi = lane >> 4;
    const int t = wid * 64 + lane;

    f32x4 acc[4][4];
    #pragma unroll
    for (int mf = 0; mf < 4; ++mf)
        #pragma unroll
        for (int nf = 0; nf < 4; ++nf)
            acc[mf][nf] = (f32x4){0.f, 0.f, 0.f, 0.f};

    if (t < 128) {
        int li = t & 3, b = (t >> 2) & 7, r = t >> 5;       // r 0..3
        int L = (li == 0) ? 0 : 64 + li;
        *(uint4*)&smem[(r * 68 + L) * CPITCH + b * 4] = make_uint4(0u, 0u, 0u, 0u);
    }
    {
        const int q = t & 63, rc = t >> 6;
        const int r = rc >> 1, half = rc & 1;
        const int y = y0 - 1 + r;
        const bool valid = (q < WW) && (y >= 0) && (y < HH);
        const float* xb = x + (((size_t)n * CIN + half * 32) * HH + (valid ? y : 0)) * WW + q;
        const int base = (r * 68 + q + 1) * CPITCH + half * 16;
        #pragma unroll
        for (int u = 0; u < 4; ++u) {
            unsigned int dh[4];
            #pragma unroll
            for (int dd = 0; dd < 4; ++dd) {
                float v0 = valid ? xb[(size_t)(u * 8 + dd * 2) * HW] : 0.f;
                float v1 = valid ? xb[(size_t)(u * 8 + dd * 2 + 1) * HW] : 0.f;
                dh[dd] = f16b(v0) | (f16b(v1) << 16);
            }
            *(uint4*)&smem[base + u * 4] = make_uint4(dh[0], dh[1], dh[2], dh[3]);
        }
    }
    __syncthreads();

    for (int cc = 0; cc < 2; ++cc) {
        #pragma unroll
        for (int tap = 0; tap < 9; ++tap) {
            const int ky = tap / 3, kx = tap - ky * 3;
            fragh_u ah[4];
            #pragma unroll
            for (int mf = 0; mf < 4; ++mf) {
                size_t fi = ((size_t)((cc * 9 + tap) * 16 + mg * 4 + mf) * 64 + lane) * 8;
                ah[mf].u = *(const uint4*)(whA + fi);
            }
            #pragma unroll
            for (int nf = 0; nf < 4; ++nf) {
                const int R = (ng + ky) * 68 + nf * 16 + lcol + kx;
                fragh_u bh;
                bh.u = *(const uint4*)&smem[R * CPITCH + cc * 16 + hi * 4];
                #pragma unroll
                for (int mf = 0; mf < 4; ++mf)
                    acc[mf][nf] = __builtin_amdgcn_mfma_f32_16x16x32_f16(ah[mf].h, bh.h, acc[mf][nf], 0, 0, 0);
            }
        }
    }
    const int yrow = y0 + ng;
    #pragma unroll
    for (int mf = 0; mf < 4; ++mf) {
        #pragma unroll
        for (int reg = 0; reg < 4; ++reg) {
            const int oc = mg * 64 + mf * 16 + hi * 4 + reg;
            const float mv = maskF[oc];
            float* ob = out + (((size_t)n * OCH + oc) * HH + yrow) * WW;
            #pragma unroll
            for (int nf = 0; nf < 4; ++nf) {
                int col = nf * 16 + lcol;
                if (col < WW) ob[col] = acc[mf][nf][reg] * mv;
            }
        }
    }
}

extern "C" void kernel_launch(void* const* d_in, const int* in_sizes, int n_in,
                              void* d_out, int out_size, void* d_ws, size_t ws_size,
                              hipStream_t stream)
{
    const float* x    = (const float*)d_in[0];
    const float* kern = (const float*)d_in[1];
    const float* a    = (const float*)d_in[2];

    float* out       = (float*)d_out;
    float* o_tallied = out + (size_t)NN * OCH * HW;
    float* o_indices = o_tallied + NH * TS;
    float* o_mask    = o_indices + NH;

    float* ws = (float*)d_ws;
    float* aT       = ws;                      // 24120 (pad 24320)
    float* scale    = ws + 24320;              // 1 (pad 64)
    float* ctab     = ws + 24384;              // 360 (pad 384)
    float* maskF    = ws + 24768;              // 256
    int*   bucket_k = (int*)(ws + 25024);      // 2048
    int*   tallied  = (int*)(ws + 27072);      // 512
    unsigned short* whA = (unsigned short*)(ws + 27584);    // 288*64*8 us = 73728 f
    unsigned short* vaH = (unsigned short*)(ws + 101312);   // 54*64*8 us = 13824 f
    unsigned short* vaL = (unsigned short*)(ws + 115136);   // 13824 f

    kA1<<<32, 256, 0, stream>>>(kern, a, aT, ctab, tallied, scale);
    kA2<<<4, dim3(64, 4), 0, stream>>>(kern, aT, scale, bucket_k);
    kW<<<342, 64, 0, stream>>>(kern, a, whA, vaH, vaL);
    kV<<<dim3(HH, NN), dim3(64, 8), 0, stream>>>(x, vaH, vaL, ctab, tallied);
    kC<<<1, 256, 0, stream>>>(tallied, bucket_k, o_tallied, o_indices, o_mask, maskF);
    kD<<<dim3(28, NN), dim3(64, 8), 0, stream>>>(x, whA, maskF, out);
}

// Round 5
// 201.826 us; speedup vs baseline: 4.3882x; 1.1911x over previous
//
#include <hip/hip_runtime.h>
#include <math.h>

#define NH 8
#define BITS_ 5
#define NB 40
#define TS 64
#define MAUG 27
#define CIN 64
#define HH 56
#define WW 56
#define NN 32
#define OCH 256
#define DK 576
#define DPM 603
#define HW (HH*WW)

#define CP 20              // dwords per (r,L) cell: 16 data + 4 pad
#define TILE 5440          // 4 rows * 68 cols * CP (dwords), per precision tile

typedef __attribute__((ext_vector_type(4))) float f32x4;
typedef __attribute__((ext_vector_type(8))) _Float16 f16x8;
typedef union { uint4 u; f16x8 h; } fragh_u;

__device__ __forceinline__ unsigned int f16b(float v) {
    union { _Float16 h; unsigned short u; } cv;
    cv.h = (_Float16)v;
    return (unsigned int)cv.u;
}
__device__ __forceinline__ float f16tof(unsigned int b) {
    union { _Float16 h; unsigned short u; } cv;
    cv.u = (unsigned short)b;
    return (float)cv.h;
}

// ---------------- kP: all prep (aT, ctab, zero tallied, norm partials, weight pack) ----
__global__ void kP(const float* __restrict__ kern, const float* __restrict__ a,
                   float* __restrict__ aT, float* __restrict__ ctab,
                   int* __restrict__ tallied, float* __restrict__ normP,
                   unsigned short* __restrict__ whA,
                   unsigned short* __restrict__ vaH, unsigned short* __restrict__ vaL)
{
    const int bid = blockIdx.x;
    const int t = threadIdx.x;
    if (bid < 32) {                       // transpose a -> aT
        for (int idx = bid * 256 + t; idx < DPM * NB; idx += 32 * 256) {
            int d = idx / NB, j = idx - d * NB;
            aT[idx] = a[j * DPM + d];
        }
    } else if (bid == 32) {               // ctab + zero tallied
        for (int g = t; g < 9 * NB; g += 256) {
            int pat = g / NB, j = g - pat * NB;
            int ry = pat / 3, rx = pat % 3;
            float s = 0.f;
            for (int ky = 0; ky < 3; ++ky) {
                if (ry == 0 && ky == 0) continue;
                if (ry == 2 && ky == 2) continue;
                for (int kx = 0; kx < 3; ++kx) {
                    if (rx == 0 && kx == 0) continue;
                    if (rx == 2 && kx == 2) continue;
                    for (int mc = 0; mc < 3; ++mc)
                        s += a[j * DPM + DK + mc * 9 + ky * 3 + kx];
                }
            }
            ctab[g] = 0.5f * s;
        }
        for (int g = t; g < NH * TS; g += 256) tallied[g] = 0;
    } else if (bid < 37) {                // norm partials (coalesced-ish streaming)
        int g = (bid - 33) * 256 + t;     // 1024 = 256 oc * 4 parts
        int oc = g >> 2, part = g & 3;
        const float4* p = (const float4*)(kern + oc * DK + part * 144);
        float sq = 0.f;
        #pragma unroll 4
        for (int i = 0; i < 36; ++i) {
            float4 v = p[i];
            sq += v.x * v.x + v.y * v.y + v.z * v.z + v.w * v.w;
        }
        normP[g] = sq;
    } else {                              // weight packing (342 frags * 64 lanes)
        int idx = (bid - 37) * 256 + t;
        int f = idx >> 6, lane = idx & 63;
        if (f < 288) {                    // main conv: single f16 A-frags
            const int kidxG = f >> 4, mf = f & 15;
            const int tap = kidxG % 9, cc = kidxG / 9;
            const int oc = mf * 16 + (lane & 15);
            const int cbase = cc * 32 + (lane >> 4) * 8;
            unsigned int hs[8];
            #pragma unroll
            for (int j = 0; j < 8; ++j)
                hs[j] = f16b(kern[oc * DK + (cbase + j) * 9 + tap]);
            unsigned int* p = (unsigned int*)(whA + ((size_t)f * 64 + lane) * 8);
            #pragma unroll
            for (int w2 = 0; w2 < 4; ++w2)
                p[w2] = hs[2 * w2] | (hs[2 * w2 + 1] << 16);
        } else if (f < 342) {             // vote: f16 hi/lo A-frags
            const int fv = f - 288;
            const int kidxG = fv / 3, mfv = fv % 3;
            const int tap = kidxG % 9, cc = kidxG / 9;
            const int j = mfv * 16 + (lane & 15);
            const int cbase = cc * 32 + (lane >> 4) * 8;
            unsigned int hs[8], ls[8];
            #pragma unroll
            for (int jj = 0; jj < 8; ++jj) {
                float w = (j < NB) ? a[j * DPM + (cbase + jj) * 9 + tap] : 0.f;
                unsigned int h = f16b(w);
                unsigned int l = f16b(w - f16tof(h));
                hs[jj] = h; ls[jj] = l;
            }
            unsigned int* ph = (unsigned int*)(vaH + ((size_t)fv * 64 + lane) * 8);
            unsigned int* pl = (unsigned int*)(vaL + ((size_t)fv * 64 + lane) * 8);
            #pragma unroll
            for (int w2 = 0; w2 < 4; ++w2) {
                ph[w2] = hs[2 * w2] | (hs[2 * w2 + 1] << 16);
                pl[w2] = ls[2 * w2] | (ls[2 * w2 + 1] << 16);
            }
        }
    }
}

// ---------------- kA2: hash kernel vectors (coalesced via LDS chunk transpose) --------
__global__ void __launch_bounds__(256) kA2(const float* __restrict__ kern,
        const float* __restrict__ aT, const float* __restrict__ normP,
        int* __restrict__ bucket_k)
{
    __shared__ float lT[64][65];
    __shared__ float red[3 * 41 * 64];
    const int lane = threadIdx.x;
    const int ty = threadIdx.y;
    const int t = ty * 64 + lane;
    const int oc0 = blockIdx.x * 64;

    // global-max norm -> scale (redundant per block, no atomics)
    red[t] = fmaxf(fmaxf(normP[t], normP[t + 256]), fmaxf(normP[t + 512], normP[t + 768]));
    __syncthreads();
    for (int s2 = 128; s2 > 0; s2 >>= 1) {
        if (t < s2) red[t] = fmaxf(red[t], red[t + s2]);
        __syncthreads();
    }
    const float s = 0.83f / sqrtf(red[0]);
    __syncthreads();

    float acc[NB];
    #pragma unroll
    for (int j = 0; j < NB; ++j) acc[j] = 0.f;
    float sq = 0.f;

    for (int ch = 0; ch < 9; ++ch) {
        const int d0 = ch * 64;
        __syncthreads();
        #pragma unroll
        for (int i = 0; i < 16; ++i)   // stage 64 oc x 64 d, coalesced reads
            lT[lane][ty * 16 + i] = kern[(size_t)(oc0 + ty * 16 + i) * DK + d0 + lane];
        __syncthreads();
        #pragma unroll
        for (int i = 0; i < 16; ++i) {
            const int dl = ty * 16 + i;
            float xv = s * lT[dl][lane];
            sq += xv * xv;
            const float* wp = &aT[(d0 + dl) * NB];
            #pragma unroll
            for (int j = 0; j < NB; ++j) acc[j] += xv * wp[j];
        }
    }
    __syncthreads();
    if (ty > 0) {
        #pragma unroll
        for (int j = 0; j < NB; ++j) red[((ty - 1) * 41 + j) * 64 + lane] = acc[j];
        red[((ty - 1) * 41 + 40) * 64 + lane] = sq;
    }
    __syncthreads();
    if (ty == 0) {
        #pragma unroll
        for (int j = 0; j < NB; ++j)
            acc[j] += red[j * 64 + lane] + red[(41 + j) * 64 + lane] + red[(82 + j) * 64 + lane];
        sq += red[40 * 64 + lane] + red[(41 + 40) * 64 + lane] + red[(82 + 40) * 64 + lane];
        float pv = sq;
        for (int m = 0; m < MAUG; ++m) {
            const float* wp = &aT[(DK + m) * NB];
            #pragma unroll
            for (int j = 0; j < NB; ++j) acc[j] += pv * wp[j];
            pv = pv * pv;
        }
        #pragma unroll
        for (int h = 0; h < NH; ++h) {
            int b = 0;
            #pragma unroll
            for (int bb = 0; bb < BITS_; ++bb)
                if (acc[h * BITS_ + bb] > 0.f) b |= (1 << bb);
            bucket_k[h * OCH + oc0 + lane] = b & (TS - 1);
        }
    }
}

// ---------------- kM: merged main conv + (VOTE) vote conv -----------------------------
// grid (28, NN), block (64,8). Tile: 128 oc x 2 rows. 2 cc phases of 32 channels.
// VOTE=1 instance covers oc 0..127 and computes votes; VOTE=0 covers oc 128..255.
template<int VOTE>
__global__ void __launch_bounds__(512) kM(const float* __restrict__ x,
        const unsigned short* __restrict__ whA,
        const unsigned short* __restrict__ vaH, const unsigned short* __restrict__ vaL,
        const float* __restrict__ ctab, int* __restrict__ tallied,
        float* __restrict__ out)
{
    __shared__ unsigned int smem[2 * TILE];     // hi tile, lo tile (lo used iff VOTE)
    const int lane = threadIdx.x, wid = threadIdx.y;
    const int y0 = blockIdx.x * 2, n = blockIdx.y;
    const int mg = wid & 3, ng = wid >> 2;
    const int lcol = lane & 15, hi4 = lane >> 4;
    const int t = wid * 64 + lane;
    const int mfbase = VOTE ? 0 : 8;

    f32x4 acc[2][4];
    #pragma unroll
    for (int mfl = 0; mfl < 2; ++mfl)
        #pragma unroll
        for (int nf = 0; nf < 4; ++nf)
            acc[mfl][nf] = (f32x4){0.f, 0.f, 0.f, 0.f};
    f32x4 vacc[3];
    if (VOTE) {
        vacc[0] = (f32x4){0.f, 0.f, 0.f, 0.f};
        vacc[1] = (f32x4){0.f, 0.f, 0.f, 0.f};
        vacc[2] = (f32x4){0.f, 0.f, 0.f, 0.f};
    }

    if (t < 128) {                              // zero pad cells (L=0,65,66,67)
        int b = t & 3, tile = (t >> 2) & 1, li = (t >> 3) & 3, r = (t >> 5) & 3;
        int L = (li == 0) ? 0 : 64 + li;
        *(uint4*)&smem[tile * TILE + (r * 68 + L) * CP + b * 4] = make_uint4(0u, 0u, 0u, 0u);
    }

    // per-thread staging geometry: q=col (lane), rc = wid -> (row, 16ch half)
    const int q = lane;
    const int r = wid >> 1, half = wid & 1;
    const int y = y0 - 1 + r;
    const bool valid = (q < WW) && (y >= 0) && (y < HH);
    const int sbase = (r * 68 + q + 1) * CP + half * 8;

    for (int cc = 0; cc < 2; ++cc) {
        __syncthreads();
        {   // stage 32 channels (hi f16; +lo if VOTE)
            const float* xb = x + (((size_t)n * CIN + cc * 32 + half * 16) * HH +
                                   (valid ? y : 0)) * WW + q;
            #pragma unroll
            for (int u = 0; u < 2; ++u) {
                unsigned int dh[4], dl[4];
                #pragma unroll
                for (int dd = 0; dd < 4; ++dd) {
                    float v0 = valid ? xb[(size_t)(u * 8 + dd * 2) * HW] : 0.f;
                    float v1 = valid ? xb[(size_t)(u * 8 + dd * 2 + 1) * HW] : 0.f;
                    unsigned int h0 = f16b(v0), h1 = f16b(v1);
                    dh[dd] = h0 | (h1 << 16);
                    if (VOTE) {
                        unsigned int l0 = f16b(v0 - f16tof(h0));
                        unsigned int l1 = f16b(v1 - f16tof(h1));
                        dl[dd] = l0 | (l1 << 16);
                    }
                }
                *(uint4*)&smem[sbase + u * 4] = make_uint4(dh[0], dh[1], dh[2], dh[3]);
                if (VOTE)
                    *(uint4*)&smem[TILE + sbase + u * 4] = make_uint4(dl[0], dl[1], dl[2], dl[3]);
            }
        }
        __syncthreads();

        #pragma unroll
        for (int tap = 0; tap < 9; ++tap) {
            const int ky = tap / 3, kx = tap - ky * 3;
            const int kidx = cc * 9 + tap;
            fragh_u ah0, ah1;
            ah0.u = *(const uint4*)(whA + (((size_t)kidx * 16 + mfbase + mg * 2) * 64 + lane) * 8);
            ah1.u = *(const uint4*)(whA + (((size_t)kidx * 16 + mfbase + mg * 2 + 1) * 64 + lane) * 8);
            #pragma unroll
            for (int nf = 0; nf < 4; ++nf) {
                const int R = (ng + ky) * 68 + nf * 16 + lcol + kx;
                const int ad = R * CP + hi4 * 4;
                fragh_u bh;
                bh.u = *(const uint4*)&smem[ad];
                acc[0][nf] = __builtin_amdgcn_mfma_f32_16x16x32_f16(ah0.h, bh.h, acc[0][nf], 0, 0, 0);
                acc[1][nf] = __builtin_amdgcn_mfma_f32_16x16x32_f16(ah1.h, bh.h, acc[1][nf], 0, 0, 0);
                if (VOTE && nf == mg) {
                    fragh_u bl;
                    bl.u = *(const uint4*)&smem[TILE + ad];
                    #pragma unroll
                    for (int mfv = 0; mfv < 3; ++mfv) {
                        fragh_u vh, vl;
                        size_t fi = ((size_t)(kidx * 3 + mfv) * 64 + lane) * 8;
                        vh.u = *(const uint4*)(vaH + fi);
                        vl.u = *(const uint4*)(vaL + fi);
                        vacc[mfv] = __builtin_amdgcn_mfma_f32_16x16x32_f16(vh.h, bh.h, vacc[mfv], 0, 0, 0);
                        vacc[mfv] = __builtin_amdgcn_mfma_f32_16x16x32_f16(vh.h, bl.h, vacc[mfv], 0, 0, 0);
                        vacc[mfv] = __builtin_amdgcn_mfma_f32_16x16x32_f16(vl.h, bh.h, vacc[mfv], 0, 0, 0);
                    }
                }
            }
        }
    }

    // main epilogue (unmasked; kZ zeroes inactive channels after kC)
    const int yrow = y0 + ng;
    #pragma unroll
    for (int mfl = 0; mfl < 2; ++mfl) {
        #pragma unroll
        for (int reg = 0; reg < 4; ++reg) {
            const int oc = (mfbase + mg * 2 + mfl) * 16 + hi4 * 4 + reg;
            float* ob = out + (((size_t)n * OCH + oc) * HH + yrow) * WW;
            #pragma unroll
            for (int nf = 0; nf < 4; ++nf) {
                int col = nf * 16 + lcol;
                if (col < WW) ob[col] = acc[mfl][nf][reg];
            }
        }
    }

    if (VOTE) {
        __syncthreads();                         // smem free for overlay
        float* projT = (float*)smem;
        int* hist = (int*)&smem[8192];
        const int px = mg * 16 + lcol;
        #pragma unroll
        for (int mfv = 0; mfv < 3; ++mfv)
            #pragma unroll
            for (int reg = 0; reg < 4; ++reg)
                projT[(ng * 64 + px) * 49 + mfv * 16 + hi4 * 4 + reg] = vacc[mfv][reg];
        hist[t] = 0;
        __syncthreads();
        if (t < 2 * WW) {
            const int row = t / WW, pxx = t - row * WW;
            const int yv = y0 + row;
            const int ry = (yv == 0) ? 0 : ((yv == HH - 1) ? 2 : 1);
            const int rx = (pxx == 0) ? 0 : ((pxx == WW - 1) ? 2 : 1);
            const float* ct = ctab + (ry * 3 + rx) * NB;
            const float* pr = projT + (row * 64 + pxx) * 49;
            #pragma unroll
            for (int h = 0; h < NH; ++h) {
                int b = 0;
                #pragma unroll
                for (int bb = 0; bb < BITS_; ++bb)
                    if (pr[h * BITS_ + bb] + ct[h * BITS_ + bb] > 0.f) b |= (1 << bb);
                atomicAdd(&hist[h * TS + (b & (TS - 1))], 1);
            }
        }
        __syncthreads();
        {
            int v = hist[t];
            if (v) atomicAdd(&tallied[t], v);
        }
    }
}

// ---------------- kC: argmax, mask, small outputs ----------------
__global__ void kC(const int* __restrict__ tallied, const int* __restrict__ bucket_k,
                   float* __restrict__ o_tallied, float* __restrict__ o_indices,
                   float* __restrict__ o_mask, int* __restrict__ mask_i)
{
    const int t = threadIdx.x;
    __shared__ int s_idx[NH];
    if (t < NH) {
        int best = tallied[t * TS];
        int bi = 0;
        for (int b = 1; b < TS; ++b) {
            int v = tallied[t * TS + b];
            if (v > best) { best = v; bi = b; }
        }
        s_idx[t] = bi;
        o_indices[t] = (float)bi;
    }
    for (int i = t; i < NH * TS; i += 256) o_tallied[i] = (float)tallied[i];
    __syncthreads();
    int mk = 0;
    #pragma unroll
    for (int hp = 0; hp < NH; ++hp) {
        int b = bucket_k[hp * OCH + t];
        #pragma unroll
        for (int h = 0; h < NH; ++h) mk |= (b == s_idx[h]) ? 1 : 0;
    }
    mask_i[t] = mk;
    o_mask[t] = (float)mk;
}

// ---------------- kZ: zero inactive output channels ----------------
__global__ void __launch_bounds__(256) kZ(float* __restrict__ out,
                                          const int* __restrict__ mask_i)
{
    const int b = blockIdx.x;
    const int oc = b & (OCH - 1);
    if (mask_i[oc]) return;
    const int n = b >> 8;
    float4* o = (float4*)(out + ((size_t)n * OCH + oc) * HW);
    for (int i = threadIdx.x; i < HW / 4; i += 256)
        o[i] = make_float4(0.f, 0.f, 0.f, 0.f);
}

extern "C" void kernel_launch(void* const* d_in, const int* in_sizes, int n_in,
                              void* d_out, int out_size, void* d_ws, size_t ws_size,
                              hipStream_t stream)
{
    const float* x    = (const float*)d_in[0];
    const float* kern = (const float*)d_in[1];
    const float* a    = (const float*)d_in[2];

    float* out       = (float*)d_out;
    float* o_tallied = out + (size_t)NN * OCH * HW;
    float* o_indices = o_tallied + NH * TS;
    float* o_mask    = o_indices + NH;

    float* ws = (float*)d_ws;
    float* aT       = ws;                      // 24120 -> pad 24320
    float* ctab     = ws + 24320;              // 360 -> pad 384
    float* normP    = ws + 24704;              // 1024
    int*   tallied  = (int*)(ws + 25728);      // 512
    int*   bucket_k = (int*)(ws + 26240);      // 2048
    int*   mask_i   = (int*)(ws + 28288);      // 256
    unsigned short* whA = (unsigned short*)(ws + 28544);    // 288*64*8 us = 73728 f
    unsigned short* vaH = (unsigned short*)(ws + 102272);   // 13824 f
    unsigned short* vaL = (unsigned short*)(ws + 116096);   // 13824 f

    kP<<<123, 256, 0, stream>>>(kern, a, aT, ctab, tallied, normP, whA, vaH, vaL);
    kA2<<<4, dim3(64, 4), 0, stream>>>(kern, aT, normP, bucket_k);
    kM<1><<<dim3(28, NN), dim3(64, 8), 0, stream>>>(x, whA, vaH, vaL, ctab, tallied, out);
    kM<0><<<dim3(28, NN), dim3(64, 8), 0, stream>>>(x, whA, vaH, vaL, ctab, tallied, out);
    kC<<<1, 256, 0, stream>>>(tallied, bucket_k, o_tallied, o_indices, o_mask, mask_i);
    kZ<<<NN * OCH, 256, 0, stream>>>(out, mask_i);
}

// Round 6
// 125.326 us; speedup vs baseline: 7.0667x; 1.6104x over previous
//
#include <hip/hip_runtime.h>
#include <math.h>

#define NH 8
#define BITS_ 5
#define NB 40
#define TS 64
#define MAUG 27
#define CIN 64
#define HH 56
#define WW 56
#define NN 32
#define OCH 256
#define DK 576
#define DPM 603
#define HW (HH*WW)

#define CP 20              // dwords per (r,L) cell: 16 data + 4 pad
#define TILE 5440          // 4 rows * 68 cols * CP (dwords), per precision tile

typedef __attribute__((ext_vector_type(4))) float f32x4;
typedef __attribute__((ext_vector_type(8))) _Float16 f16x8;
typedef union { uint4 u; f16x8 h; } fragh_u;

__device__ __forceinline__ unsigned int f16b(float v) {
    union { _Float16 h; unsigned short u; } cv;
    cv.h = (_Float16)v;
    return (unsigned int)cv.u;
}
__device__ __forceinline__ float f16tof(unsigned int b) {
    union { _Float16 h; unsigned short u; } cv;
    cv.u = (unsigned short)b;
    return (float)cv.h;
}

// ---------------- kP: all prep (aT, ctab, zero tallied, norm partials, weight pack) ----
__global__ void kP(const float* __restrict__ kern, const float* __restrict__ a,
                   float* __restrict__ aT, float* __restrict__ ctab,
                   int* __restrict__ tallied, float* __restrict__ normP,
                   unsigned short* __restrict__ whA,
                   unsigned short* __restrict__ vaH, unsigned short* __restrict__ vaL)
{
    const int bid = blockIdx.x;
    const int t = threadIdx.x;
    if (bid < 32) {                       // transpose a -> aT
        for (int idx = bid * 256 + t; idx < DPM * NB; idx += 32 * 256) {
            int d = idx / NB, j = idx - d * NB;
            aT[idx] = a[j * DPM + d];
        }
    } else if (bid == 32) {               // ctab + zero tallied
        for (int g = t; g < 9 * NB; g += 256) {
            int pat = g / NB, j = g - pat * NB;
            int ry = pat / 3, rx = pat % 3;
            float s = 0.f;
            for (int ky = 0; ky < 3; ++ky) {
                if (ry == 0 && ky == 0) continue;
                if (ry == 2 && ky == 2) continue;
                for (int kx = 0; kx < 3; ++kx) {
                    if (rx == 0 && kx == 0) continue;
                    if (rx == 2 && kx == 2) continue;
                    for (int mc = 0; mc < 3; ++mc)
                        s += a[j * DPM + DK + mc * 9 + ky * 3 + kx];
                }
            }
            ctab[g] = 0.5f * s;
        }
        for (int g = t; g < NH * TS; g += 256) tallied[g] = 0;
    } else if (bid < 37) {                // norm partials (coalesced-ish streaming)
        int g = (bid - 33) * 256 + t;     // 1024 = 256 oc * 4 parts
        int oc = g >> 2, part = g & 3;
        const float4* p = (const float4*)(kern + oc * DK + part * 144);
        float sq = 0.f;
        #pragma unroll 4
        for (int i = 0; i < 36; ++i) {
            float4 v = p[i];
            sq += v.x * v.x + v.y * v.y + v.z * v.z + v.w * v.w;
        }
        normP[g] = sq;
    } else {                              // weight packing (342 frags * 64 lanes)
        int idx = (bid - 37) * 256 + t;
        int f = idx >> 6, lane = idx & 63;
        if (f < 288) {                    // main conv: single f16 A-frags
            const int kidxG = f >> 4, mf = f & 15;
            const int tap = kidxG % 9, cc = kidxG / 9;
            const int oc = mf * 16 + (lane & 15);
            const int cbase = cc * 32 + (lane >> 4) * 8;
            unsigned int hs[8];
            #pragma unroll
            for (int j = 0; j < 8; ++j)
                hs[j] = f16b(kern[oc * DK + (cbase + j) * 9 + tap]);
            unsigned int* p = (unsigned int*)(whA + ((size_t)f * 64 + lane) * 8);
            #pragma unroll
            for (int w2 = 0; w2 < 4; ++w2)
                p[w2] = hs[2 * w2] | (hs[2 * w2 + 1] << 16);
        } else if (f < 342) {             // vote: f16 hi/lo A-frags
            const int fv = f - 288;
            const int kidxG = fv / 3, mfv = fv % 3;
            const int tap = kidxG % 9, cc = kidxG / 9;
            const int j = mfv * 16 + (lane & 15);
            const int cbase = cc * 32 + (lane >> 4) * 8;
            unsigned int hs[8], ls[8];
            #pragma unroll
            for (int jj = 0; jj < 8; ++jj) {
                float w = (j < NB) ? a[j * DPM + (cbase + jj) * 9 + tap] : 0.f;
                unsigned int h = f16b(w);
                unsigned int l = f16b(w - f16tof(h));
                hs[jj] = h; ls[jj] = l;
            }
            unsigned int* ph = (unsigned int*)(vaH + ((size_t)fv * 64 + lane) * 8);
            unsigned int* pl = (unsigned int*)(vaL + ((size_t)fv * 64 + lane) * 8);
            #pragma unroll
            for (int w2 = 0; w2 < 4; ++w2) {
                ph[w2] = hs[2 * w2] | (hs[2 * w2 + 1] << 16);
                pl[w2] = ls[2 * w2] | (ls[2 * w2 + 1] << 16);
            }
        }
    }
}

// ---------------- kH: hash kernel vectors, one block per oc -------------------------
// 4 waves: wave ty covers d in [ty*144, ty*144+144); lane j<40 = hash row.
// Partial-sum split and reduction grouping match rounds 1-4 (passing config).
__global__ void __launch_bounds__(256) kH(const float* __restrict__ kern,
        const float* __restrict__ aT, const float* __restrict__ normP,
        int* __restrict__ bucket_k)
{
    __shared__ float xs[DK];
    __shared__ float red[256];
    __shared__ float accR[3 * 41];
    __shared__ float proj[NB];
    const int t = threadIdx.x;
    const int lane = t & 63, ty = t >> 6;
    const int oc = blockIdx.x;

    red[t] = fmaxf(fmaxf(normP[t], normP[t + 256]), fmaxf(normP[t + 512], normP[t + 768]));
    __syncthreads();
    for (int s = 128; s > 0; s >>= 1) {
        if (t < s) red[t] = fmaxf(red[t], red[t + s]);
        __syncthreads();
    }
    const float scale = 0.83f / sqrtf(red[0]);
    for (int i = t; i < DK; i += 256) xs[i] = scale * kern[(size_t)oc * DK + i];
    __syncthreads();

    const int j = (lane < NB) ? lane : (NB - 1);
    float acc = 0.f, sq = 0.f;
    const int d0 = ty * 144;
    for (int d = d0; d < d0 + 144; ++d) {
        float xv = xs[d];
        sq += xv * xv;
        acc += xv * aT[d * NB + j];
    }
    if (ty > 0) {
        if (lane < NB) accR[(ty - 1) * 41 + lane] = acc;
        if (lane == NB) accR[(ty - 1) * 41 + 40] = sq;
    }
    __syncthreads();
    if (ty == 0 && lane < NB) {
        acc += (accR[lane] + accR[41 + lane]) + accR[82 + lane];
        sq += (accR[40] + accR[81]) + accR[122];
        float pv = sq;
        for (int m = 0; m < MAUG; ++m) {
            acc += pv * aT[(DK + m) * NB + lane];
            pv = pv * pv;
        }
        proj[lane] = acc;
    }
    __syncthreads();
    if (t < NH) {
        int b = 0;
        #pragma unroll
        for (int bb = 0; bb < BITS_; ++bb)
            if (proj[t * BITS_ + bb] > 0.f) b |= (1 << bb);
        bucket_k[t * OCH + oc] = b & (TS - 1);
    }
}

// ---------------- kM: merged main conv + (VOTE) vote conv -----------------------------
// grid (28, NN), block (64,8). Tile: 128 oc x 2 rows. 2 cc phases of 32 channels.
// VOTE=1 instance covers oc 0..127 and computes votes (unmasked out);
// VOTE=0 covers oc 128..255 and applies the mask in its epilogue.
template<int VOTE>
__global__ void __launch_bounds__(512) kM(const float* __restrict__ x,
        const unsigned short* __restrict__ whA,
        const unsigned short* __restrict__ vaH, const unsigned short* __restrict__ vaL,
        const float* __restrict__ ctab, int* __restrict__ tallied,
        const float* __restrict__ maskF, float* __restrict__ out)
{
    __shared__ unsigned int smem[2 * TILE];     // hi tile, lo tile (lo used iff VOTE)
    const int lane = threadIdx.x, wid = threadIdx.y;
    const int y0 = blockIdx.x * 2, n = blockIdx.y;
    const int mg = wid & 3, ng = wid >> 2;
    const int lcol = lane & 15, hi4 = lane >> 4;
    const int t = wid * 64 + lane;
    const int mfbase = VOTE ? 0 : 8;

    f32x4 acc[2][4];
    #pragma unroll
    for (int mfl = 0; mfl < 2; ++mfl)
        #pragma unroll
        for (int nf = 0; nf < 4; ++nf)
            acc[mfl][nf] = (f32x4){0.f, 0.f, 0.f, 0.f};
    f32x4 vacc[3];
    if (VOTE) {
        vacc[0] = (f32x4){0.f, 0.f, 0.f, 0.f};
        vacc[1] = (f32x4){0.f, 0.f, 0.f, 0.f};
        vacc[2] = (f32x4){0.f, 0.f, 0.f, 0.f};
    }

    if (t < 128) {                              // zero pad cells (L=0,65,66,67)
        int b = t & 3, tile = (t >> 2) & 1, li = (t >> 3) & 3, r = (t >> 5) & 3;
        int L = (li == 0) ? 0 : 64 + li;
        *(uint4*)&smem[tile * TILE + (r * 68 + L) * CP + b * 4] = make_uint4(0u, 0u, 0u, 0u);
    }

    const int q = lane;
    const int r = wid >> 1, half = wid & 1;
    const int y = y0 - 1 + r;
    const bool valid = (q < WW) && (y >= 0) && (y < HH);
    const int sbase = (r * 68 + q + 1) * CP + half * 8;

    for (int cc = 0; cc < 2; ++cc) {
        __syncthreads();
        {   // stage 32 channels (hi f16; +lo if VOTE)
            const float* xb = x + (((size_t)n * CIN + cc * 32 + half * 16) * HH +
                                   (valid ? y : 0)) * WW + q;
            #pragma unroll
            for (int u = 0; u < 2; ++u) {
                unsigned int dh[4], dl[4];
                #pragma unroll
                for (int dd = 0; dd < 4; ++dd) {
                    float v0 = valid ? xb[(size_t)(u * 8 + dd * 2) * HW] : 0.f;
                    float v1 = valid ? xb[(size_t)(u * 8 + dd * 2 + 1) * HW] : 0.f;
                    unsigned int h0 = f16b(v0), h1 = f16b(v1);
                    dh[dd] = h0 | (h1 << 16);
                    if (VOTE) {
                        unsigned int l0 = f16b(v0 - f16tof(h0));
                        unsigned int l1 = f16b(v1 - f16tof(h1));
                        dl[dd] = l0 | (l1 << 16);
                    }
                }
                *(uint4*)&smem[sbase + u * 4] = make_uint4(dh[0], dh[1], dh[2], dh[3]);
                if (VOTE)
                    *(uint4*)&smem[TILE + sbase + u * 4] = make_uint4(dl[0], dl[1], dl[2], dl[3]);
            }
        }
        __syncthreads();

        #pragma unroll
        for (int tap = 0; tap < 9; ++tap) {
            const int ky = tap / 3, kx = tap - ky * 3;
            const int kidx = cc * 9 + tap;
            fragh_u ah0, ah1;
            ah0.u = *(const uint4*)(whA + (((size_t)kidx * 16 + mfbase + mg * 2) * 64 + lane) * 8);
            ah1.u = *(const uint4*)(whA + (((size_t)kidx * 16 + mfbase + mg * 2 + 1) * 64 + lane) * 8);
            #pragma unroll
            for (int nf = 0; nf < 4; ++nf) {
                const int R = (ng + ky) * 68 + nf * 16 + lcol + kx;
                const int ad = R * CP + hi4 * 4;
                fragh_u bh;
                bh.u = *(const uint4*)&smem[ad];
                acc[0][nf] = __builtin_amdgcn_mfma_f32_16x16x32_f16(ah0.h, bh.h, acc[0][nf], 0, 0, 0);
                acc[1][nf] = __builtin_amdgcn_mfma_f32_16x16x32_f16(ah1.h, bh.h, acc[1][nf], 0, 0, 0);
                if (VOTE && nf == mg) {
                    fragh_u bl;
                    bl.u = *(const uint4*)&smem[TILE + ad];
                    #pragma unroll
                    for (int mfv = 0; mfv < 3; ++mfv) {
                        fragh_u vh, vl;
                        size_t fi = ((size_t)(kidx * 3 + mfv) * 64 + lane) * 8;
                        vh.u = *(const uint4*)(vaH + fi);
                        vl.u = *(const uint4*)(vaL + fi);
                        vacc[mfv] = __builtin_amdgcn_mfma_f32_16x16x32_f16(vh.h, bh.h, vacc[mfv], 0, 0, 0);
                        vacc[mfv] = __builtin_amdgcn_mfma_f32_16x16x32_f16(vh.h, bl.h, vacc[mfv], 0, 0, 0);
                        vacc[mfv] = __builtin_amdgcn_mfma_f32_16x16x32_f16(vl.h, bh.h, vacc[mfv], 0, 0, 0);
                    }
                }
            }
        }
    }

    // epilogue: VOTE=1 unmasked (kZ cleans up); VOTE=0 masked (kC already ran)
    const int yrow = y0 + ng;
    #pragma unroll
    for (int mfl = 0; mfl < 2; ++mfl) {
        #pragma unroll
        for (int reg = 0; reg < 4; ++reg) {
            const int oc = (mfbase + mg * 2 + mfl) * 16 + hi4 * 4 + reg;
            const float mv = VOTE ? 1.0f : maskF[oc];
            float* ob = out + (((size_t)n * OCH + oc) * HH + yrow) * WW;
            #pragma unroll
            for (int nf = 0; nf < 4; ++nf) {
                int col = nf * 16 + lcol;
                if (col < WW) ob[col] = acc[mfl][nf][reg] * mv;
            }
        }
    }

    if (VOTE) {
        __syncthreads();
        float* projT = (float*)smem;
        int* hist = (int*)&smem[8192];
        const int px = mg * 16 + lcol;
        #pragma unroll
        for (int mfv = 0; mfv < 3; ++mfv)
            #pragma unroll
            for (int reg = 0; reg < 4; ++reg)
                projT[(ng * 64 + px) * 49 + mfv * 16 + hi4 * 4 + reg] = vacc[mfv][reg];
        hist[t] = 0;
        __syncthreads();
        if (t < 2 * WW) {
            const int row = t / WW, pxx = t - row * WW;
            const int yv = y0 + row;
            const int ry = (yv == 0) ? 0 : ((yv == HH - 1) ? 2 : 1);
            const int rx = (pxx == 0) ? 0 : ((pxx == WW - 1) ? 2 : 1);
            const float* ct = ctab + (ry * 3 + rx) * NB;
            const float* pr = projT + (row * 64 + pxx) * 49;
            #pragma unroll
            for (int h = 0; h < NH; ++h) {
                int b = 0;
                #pragma unroll
                for (int bb = 0; bb < BITS_; ++bb)
                    if (pr[h * BITS_ + bb] + ct[h * BITS_ + bb] > 0.f) b |= (1 << bb);
                atomicAdd(&hist[h * TS + (b & (TS - 1))], 1);
            }
        }
        __syncthreads();
        {
            int v = hist[t];
            if (v) atomicAdd(&tallied[t], v);
        }
    }
}

// ---------------- kC: argmax, mask, small outputs ----------------
__global__ void kC(const int* __restrict__ tallied, const int* __restrict__ bucket_k,
                   float* __restrict__ o_tallied, float* __restrict__ o_indices,
                   float* __restrict__ o_mask, int* __restrict__ mask_i,
                   float* __restrict__ maskF)
{
    const int t = threadIdx.x;
    __shared__ int s_idx[NH];
    if (t < NH) {
        int best = tallied[t * TS];
        int bi = 0;
        for (int b = 1; b < TS; ++b) {
            int v = tallied[t * TS + b];
            if (v > best) { best = v; bi = b; }
        }
        s_idx[t] = bi;
        o_indices[t] = (float)bi;
    }
    for (int i = t; i < NH * TS; i += 256) o_tallied[i] = (float)tallied[i];
    __syncthreads();
    int mk = 0;
    #pragma unroll
    for (int hp = 0; hp < NH; ++hp) {
        int b = bucket_k[hp * OCH + t];
        #pragma unroll
        for (int h = 0; h < NH; ++h) mk |= (b == s_idx[h]) ? 1 : 0;
    }
    mask_i[t] = mk;
    maskF[t] = (float)mk;
    o_mask[t] = (float)mk;
}

// ---------------- kZ: zero inactive output channels (lower half only) ----------------
__global__ void __launch_bounds__(256) kZ(float* __restrict__ out,
                                          const int* __restrict__ mask_i)
{
    const int b = blockIdx.x;
    const int oc = b & 127;               // oc 0..127 (kM<0> masks the upper half)
    if (mask_i[oc]) return;
    const int n = b >> 7;
    float4* o = (float4*)(out + ((size_t)n * OCH + oc) * HW);
    for (int i = threadIdx.x; i < HW / 4; i += 256)
        o[i] = make_float4(0.f, 0.f, 0.f, 0.f);
}

extern "C" void kernel_launch(void* const* d_in, const int* in_sizes, int n_in,
                              void* d_out, int out_size, void* d_ws, size_t ws_size,
                              hipStream_t stream)
{
    const float* x    = (const float*)d_in[0];
    const float* kern = (const float*)d_in[1];
    const float* a    = (const float*)d_in[2];

    float* out       = (float*)d_out;
    float* o_tallied = out + (size_t)NN * OCH * HW;
    float* o_indices = o_tallied + NH * TS;
    float* o_mask    = o_indices + NH;

    float* ws = (float*)d_ws;
    float* aT       = ws;                      // 24120 -> pad 24320
    float* ctab     = ws + 24320;              // 360 -> pad 384
    float* normP    = ws + 24704;              // 1024
    int*   tallied  = (int*)(ws + 25728);      // 512
    int*   bucket_k = (int*)(ws + 26240);      // 2048
    int*   mask_i   = (int*)(ws + 28288);      // 256
    float* maskF    = ws + 28544;              // 256
    unsigned short* whA = (unsigned short*)(ws + 28800);    // 73728 f
    unsigned short* vaH = (unsigned short*)(ws + 102528);   // 13824 f
    unsigned short* vaL = (unsigned short*)(ws + 116352);   // 13824 f

    kP<<<123, 256, 0, stream>>>(kern, a, aT, ctab, tallied, normP, whA, vaH, vaL);
    kH<<<OCH, 256, 0, stream>>>(kern, aT, normP, bucket_k);
    kM<1><<<dim3(28, NN), dim3(64, 8), 0, stream>>>(x, whA, vaH, vaL, ctab, tallied, maskF, out);
    kC<<<1, 256, 0, stream>>>(tallied, bucket_k, o_tallied, o_indices, o_mask, mask_i, maskF);
    kM<0><<<dim3(28, NN), dim3(64, 8), 0, stream>>>(x, whA, vaH, vaL, ctab, tallied, maskF, out);
    kZ<<<NN * 128, 256, 0, stream>>>(out, mask_i);
}